// Round 1
// baseline (920.036 us; speedup 1.0000x reference)
//
#include <hip/hip_runtime.h>

constexpr int HD = 128;   // hidden dim
constexpr int BM = 64;    // rows per block
constexpr int BK = 32;    // k-tile
constexpr int APAD = 44;  // padded A-tile stride (floats): 16B-aligned, kills stride-40 bank alias

// C = [relu](A1@W1 [+ A2@W2] + bias), A: [nrows][128] f32 row-major, W: [128][NCOL]
template<int NCOL, bool RELU, bool DUAL>
__global__ __launch_bounds__(256, DUAL ? 2 : 4)
void k_gemm(const float* __restrict__ A1, const float* __restrict__ W1,
            const float* __restrict__ A2, const float* __restrict__ W2,
            const float* __restrict__ bias, float* __restrict__ C, int nrows)
{
    constexpr int CPT = 8;              // cols per thread
    constexpr int TCN = NCOL / CPT;     // threads across cols (16 or 8)
    constexpr int GROUPS = 256 / TCN;   // row groups (16 or 32)
    constexpr int RPT = BM / GROUPS;    // rows per thread (4 or 2)

    __shared__ float As1[BM][APAD];
    __shared__ float Ws1[BK][NCOL];
    __shared__ float As2[DUAL ? BM : 1][DUAL ? APAD : 1];
    __shared__ float Ws2[DUAL ? BK : 1][DUAL ? NCOL : 1];

    const int tid = threadIdx.x;
    const int tc = tid % TCN;
    const int tr = tid / TCN;
    const long row0 = (long)blockIdx.x * BM;

    float acc[RPT][CPT];
#pragma unroll
    for (int i = 0; i < RPT; ++i)
#pragma unroll
        for (int j = 0; j < CPT; ++j) acc[i][j] = 0.f;

    for (int k0 = 0; k0 < HD; k0 += BK) {
        // stage A tile(s): 64 rows x 32 k = 512 float4
#pragma unroll
        for (int it = 0; it < 2; ++it) {
            int idx = tid + it * 256;
            int r = idx >> 3;
            int kc = (idx & 7) << 2;
            long gr = row0 + r; if (gr > (long)nrows - 1) gr = (long)nrows - 1;
            *(float4*)&As1[r][kc] = *(const float4*)(A1 + gr * HD + k0 + kc);
            if constexpr (DUAL)
                *(float4*)&As2[r][kc] = *(const float4*)(A2 + gr * HD + k0 + kc);
        }
        // stage W tile(s): BK x NCOL
        constexpr int WF4 = BK * NCOL / 4;
#pragma unroll
        for (int it = 0; it < WF4 / 256; ++it) {
            int idx = tid + it * 256;
            int kr = idx / (NCOL / 4);
            int cc = (idx % (NCOL / 4)) << 2;
            *(float4*)&Ws1[kr][cc] = *(const float4*)(W1 + (long)(k0 + kr) * NCOL + cc);
            if constexpr (DUAL)
                *(float4*)&Ws2[kr][cc] = *(const float4*)(W2 + (long)(k0 + kr) * NCOL + cc);
        }
        __syncthreads();

#pragma unroll
        for (int kk = 0; kk < BK; kk += 4) {
            float4 a1v[RPT]; float4 a2v[DUAL ? RPT : 1];
#pragma unroll
            for (int i = 0; i < RPT; ++i) {
                a1v[i] = *(const float4*)&As1[tr * RPT + i][kk];
                if constexpr (DUAL) a2v[i] = *(const float4*)&As2[tr * RPT + i][kk];
            }
            const float* a1s = (const float*)a1v;
            const float* a2s = (const float*)a2v;
#pragma unroll
            for (int q = 0; q < 4; ++q) {
                float w1[8];
                *(float4*)&w1[0] = *(const float4*)&Ws1[kk + q][tc * CPT];
                *(float4*)&w1[4] = *(const float4*)&Ws1[kk + q][tc * CPT + 4];
                float w2[8];
                if constexpr (DUAL) {
                    *(float4*)&w2[0] = *(const float4*)&Ws2[kk + q][tc * CPT];
                    *(float4*)&w2[4] = *(const float4*)&Ws2[kk + q][tc * CPT + 4];
                }
#pragma unroll
                for (int i = 0; i < RPT; ++i) {
                    const float a1 = a1s[i * 4 + q];
#pragma unroll
                    for (int j = 0; j < CPT; ++j) acc[i][j] = fmaf(a1, w1[j], acc[i][j]);
                    if constexpr (DUAL) {
                        const float a2 = a2s[i * 4 + q];
#pragma unroll
                        for (int j = 0; j < CPT; ++j) acc[i][j] = fmaf(a2, w2[j], acc[i][j]);
                    }
                }
            }
        }
        __syncthreads();
    }

    float bv[8];
    *(float4*)&bv[0] = *(const float4*)(bias + tc * CPT);
    *(float4*)&bv[4] = *(const float4*)(bias + tc * CPT + 4);
#pragma unroll
    for (int i = 0; i < RPT; ++i) {
        long r = row0 + tr * RPT + i;
        if (r < nrows) {
            float o[8];
#pragma unroll
            for (int j = 0; j < CPT; ++j) {
                o[j] = acc[i][j] + bv[j];
                if constexpr (RELU) o[j] = fmaxf(o[j], 0.f);
            }
            float* cp = C + r * NCOL + tc * CPT;
            *(float4*)cp = *(float4*)&o[0];
            *(float4*)(cp + 4) = *(float4*)&o[4];
        }
    }
}

// ---- CSR build ----
__global__ void k_deg(const int* __restrict__ src, const int* __restrict__ dst,
                      int* __restrict__ deg, int nE, int n) {
    int e = blockIdx.x * 256 + threadIdx.x;
    if (e >= nE) return;
    unsigned d = (unsigned)dst[e], s = (unsigned)src[e];
    if (d < (unsigned)n && s < (unsigned)n) atomicAdd(&deg[d], 1);
}

__global__ void k_invdeg(const int* __restrict__ deg, float* __restrict__ inv_deg, int n) {
    int i = blockIdx.x * 256 + threadIdx.x;
    if (i < n) inv_deg[i] = 1.0f / fmaxf((float)deg[i], 1.0f);
}

__global__ void k_chunksum(const int* __restrict__ deg, int* __restrict__ csum, int n) {
    __shared__ int s[256];
    int t = threadIdx.x, i = blockIdx.x * 256 + t;
    s[t] = (i < n) ? deg[i] : 0;
    __syncthreads();
    for (int o = 128; o > 0; o >>= 1) { if (t < o) s[t] += s[t + o]; __syncthreads(); }
    if (t == 0) csum[blockIdx.x] = s[0];
}

__global__ void k_scanmid(const int* __restrict__ csum, int* __restrict__ cbase,
                          int* __restrict__ rowstart, int nch, int n) {
    __shared__ int s[512];
    int t = threadIdx.x;
    int v = (t < nch) ? csum[t] : 0;
    s[t] = v; __syncthreads();
    for (int off = 1; off < 512; off <<= 1) {
        int tmp = (t >= off) ? s[t - off] : 0;
        __syncthreads();
        s[t] += tmp;
        __syncthreads();
    }
    if (t < nch) cbase[t] = s[t] - v;
    if (t == nch - 1) rowstart[n] = s[t];
}

__global__ void k_scan2(const int* __restrict__ deg, const int* __restrict__ cbase,
                        int* __restrict__ rowstart, int n) {
    __shared__ int s[256];
    int t = threadIdx.x, i = blockIdx.x * 256 + t;
    int v = (i < n) ? deg[i] : 0;
    s[t] = v; __syncthreads();
    for (int off = 1; off < 256; off <<= 1) {
        int tmp = (t >= off) ? s[t - off] : 0;
        __syncthreads();
        s[t] += tmp;
        __syncthreads();
    }
    if (i < n) rowstart[i] = cbase[blockIdx.x] + s[t] - v;
}

__global__ void k_fill(const int* __restrict__ src, const int* __restrict__ dst,
                       const float* __restrict__ eattr, const int* __restrict__ rowstart,
                       int* __restrict__ cursor, int* __restrict__ csr_src,
                       float* __restrict__ csr_attr, int nE, int n) {
    int e = blockIdx.x * 256 + threadIdx.x;
    if (e >= nE) return;
    unsigned d = (unsigned)dst[e], s = (unsigned)src[e];
    if (d < (unsigned)n && s < (unsigned)n) {
        int p = rowstart[d] + atomicAdd(&cursor[d], 1);
        csr_src[p] = (int)s;
        csr_attr[p] = eattr[e];
    }
}

// agg[i] = inv_deg[i] * sum_{p in row i} relu(g[src_p] + attr_p * wlast)
__global__ __launch_bounds__(256)
void k_aggregate(const float* __restrict__ g, const int* __restrict__ cs,
                 const float* __restrict__ ca, const int* __restrict__ rs,
                 const float* __restrict__ inv_deg, const float* __restrict__ wlast,
                 float* __restrict__ agg, int n) {
    int lane = threadIdx.x & 31;
    int node = blockIdx.x * 8 + (threadIdx.x >> 5);
    if (node >= n) return;
    int c0 = lane * 4;
    float4 wl = *(const float4*)(wlast + c0);
    int p0 = rs[node], p1 = rs[node + 1];
    float ax = 0.f, ay = 0.f, az = 0.f, aw = 0.f;
    for (int p = p0; p < p1; ++p) {
        int s = cs[p];
        float a = ca[p];
        float4 gv = *(const float4*)(g + (long)s * HD + c0);
        ax += fmaxf(fmaf(a, wl.x, gv.x), 0.f);
        ay += fmaxf(fmaf(a, wl.y, gv.y), 0.f);
        az += fmaxf(fmaf(a, wl.z, gv.z), 0.f);
        aw += fmaxf(fmaf(a, wl.w, gv.w), 0.f);
    }
    float id = inv_deg[node];
    float4 o; o.x = ax * id; o.y = ay * id; o.z = az * id; o.w = aw * id;
    *(float4*)(agg + (long)node * HD + c0) = o;
}

__global__ void k_fillconst(float* p, float v, int n) {
    int i = blockIdx.x * 256 + threadIdx.x;
    if (i < n) p[i] = v;
}

extern "C" void kernel_launch(void* const* d_in, const int* in_sizes, int n_in,
                              void* d_out, int out_size, void* d_ws, size_t ws_size,
                              hipStream_t stream)
{
    const float* x     = (const float*)d_in[0];
    const float* eattr = (const float*)d_in[1];
    const float* W_lin = (const float*)d_in[2];
    const float* b_lin = (const float*)d_in[3];
    const float* W_msg = (const float*)d_in[4];
    const float* b_msg = (const float*)d_in[5];
    const float* W_l   = (const float*)d_in[6];
    const float* b_l   = (const float*)d_in[7];
    const float* W_r   = (const float*)d_in[8];
    const float* W_dec = (const float*)d_in[9];
    const float* b_dec = (const float*)d_in[10];
    const float* W_fin = (const float*)d_in[11];
    const float* b_fin = (const float*)d_in[12];
    const int*   ei    = (const int*)d_in[13];

    const int N = in_sizes[0] / HD;   // 100000
    const int E = in_sizes[1];        // 600000
    const int* srcv = ei;
    const int* dstv = ei + E;

    char* wsb = (char*)d_ws;
    size_t off = 0;
    auto carve = [&](size_t bytes) -> void* {
        void* p = wsb + off;
        off += (bytes + 255) & ~(size_t)255;
        return p;
    };
    float* B0 = (float*)carve((size_t)N * HD * 4);  // h / g / emb
    float* B2 = (float*)carve((size_t)N * HD * 4);  // agg
    float* B3 = (float*)carve((size_t)N * HD * 4);  // x (layer state)
    int*   csr_src  = (int*)carve((size_t)E * 4);
    float* csr_attr = (float*)carve((size_t)E * 4);
    int*   rowstart = (int*)carve((size_t)(N + 1) * 4);
    int*   deg      = (int*)carve((size_t)N * 4);
    int*   cursor   = (int*)carve((size_t)N * 4);
    float* inv_deg  = (float*)carve((size_t)N * 4);
    const int NCH = (N + 255) / 256;
    int* csum  = (int*)carve((size_t)NCH * 4);
    int* cbase = (int*)carve((size_t)NCH * 4);

    if (off > ws_size) {
        // workspace too small: emit zeros so the failure mode is identifiable (absmax == max|ref|)
        hipMemsetAsync(d_out, 0, (size_t)out_size * 4, stream);
        return;
    }

    hipMemsetAsync(deg, 0, (size_t)N * 4, stream);
    hipMemsetAsync(cursor, 0, (size_t)N * 4, stream);

    k_deg<<<(E + 255) / 256, 256, 0, stream>>>(srcv, dstv, deg, E, N);
    k_invdeg<<<(N + 255) / 256, 256, 0, stream>>>(deg, inv_deg, N);
    k_chunksum<<<NCH, 256, 0, stream>>>(deg, csum, N);
    k_scanmid<<<1, 512, 0, stream>>>(csum, cbase, rowstart, NCH, N);
    k_scan2<<<NCH, 256, 0, stream>>>(deg, cbase, rowstart, N);
    k_fill<<<(E + 255) / 256, 256, 0, stream>>>(srcv, dstv, eattr, rowstart, cursor,
                                                csr_src, csr_attr, E, N);

    const int GB = (N + BM - 1) / BM;
    for (int l = 0; l < 3; ++l) {
        const float* xin = (l == 0) ? x : B3;
        // h = relu(x @ W_lin + b_lin)
        k_gemm<HD, true, false><<<GB, 256, 0, stream>>>(
            xin, W_lin + (size_t)l * HD * HD, nullptr, nullptr, b_lin + l * HD, B0, N);
        // g = h @ Wm_top + b_msg   (in-place on B0; each block only touches its own rows)
        k_gemm<HD, false, false><<<GB, 256, 0, stream>>>(
            B0, W_msg + (size_t)l * (HD + 1) * HD, nullptr, nullptr, b_msg + l * HD, B0, N);
        // agg = inv_deg * sum relu(g[src] + attr * wm_last)
        k_aggregate<<<(N + 7) / 8, 256, 0, stream>>>(
            B0, csr_src, csr_attr, rowstart, inv_deg,
            W_msg + (size_t)l * (HD + 1) * HD + (size_t)HD * HD, B2, N);
        // x = relu(agg @ W_l + x @ W_r + b_l)   (in-place on B3 for l>=1; row-disjoint blocks)
        k_gemm<HD, true, true><<<GB, 256, 0, stream>>>(
            B2, W_l + (size_t)l * HD * HD, xin, W_r + (size_t)l * HD * HD, b_l + l * HD, B3, N);
    }
    // emb = relu(x @ W_dec + b_dec)
    k_gemm<HD, true, false><<<GB, 256, 0, stream>>>(B3, W_dec, nullptr, nullptr, b_dec, B0, N);
    // logits = emb @ W_fin + b_fin
    k_gemm<64, false, false><<<GB, 256, 0, stream>>>(B0, W_fin, nullptr, nullptr, b_fin,
                                                     (float*)d_out, N);
}

// Round 2
// 596.396 us; speedup vs baseline: 1.5427x; 1.5427x over previous
//
#include <hip/hip_runtime.h>

using short8 = __attribute__((ext_vector_type(8))) short;
using f32x4  = __attribute__((ext_vector_type(4))) float;

constexpr int HD = 128;

__device__ __forceinline__ unsigned short f2bf(float f) {
    unsigned u = __builtin_bit_cast(unsigned, f);
    u += 0x7fffu + ((u >> 16) & 1u);          // round-to-nearest-even
    return (unsigned short)(u >> 16);
}
__device__ __forceinline__ float bflo(unsigned u) { return __builtin_bit_cast(float, u << 16); }
__device__ __forceinline__ float bfhi(unsigned u) { return __builtin_bit_cast(float, u & 0xffff0000u); }

__device__ __forceinline__ short8 ld_frag(const unsigned short* p) {
    return *reinterpret_cast<const short8*>(p);   // 16B contiguous, aligned
}

// C = [relu](A1@W1 [+ A2@W2] + bias). A: [nrows][128] bf16 row-major.
// Wt: [NCOL][128] bf16 (transposed weights). Output bf16 or f32.
// Wave computes 64 rows x 32 cols (4 rowtiles x 2 coltiles), 4 waves/block.
// No LDS, no barriers: A/B fragments are direct 16B global loads; the k-slot
// permutation tau(lane>>4, j) is applied identically to A and B fragments,
// which leaves the MFMA dot-product invariant.
template<int NCOL, bool RELU, bool DUAL, bool F32OUT>
__global__ __launch_bounds__(256, DUAL ? 3 : 4)
void k_mm(const unsigned short* __restrict__ A1, const unsigned short* __restrict__ Wt1,
          const unsigned short* __restrict__ A2, const unsigned short* __restrict__ Wt2,
          const float* __restrict__ bias, void* __restrict__ Cout, int nrows)
{
    constexpr int WC    = NCOL / 32;     // waves across cols: 4 (NCOL=128) or 2 (64)
    constexpr int BROWS = (4 / WC) * 64; // rows per block: 64 or 128

    const int lane = threadIdx.x & 63;
    const int wave = threadIdx.x >> 6;
    const int row_base = blockIdx.x * BROWS + (wave / WC) * 64;
    const int col_base = (wave % WC) * 32;
    const int lr = lane & 15;            // row (A) / col (B,D) within 16-tile
    const int lg = lane >> 4;            // k-group
    const int koff = lg * 8;

    f32x4 acc[4][2];
#pragma unroll
    for (int rt = 0; rt < 4; ++rt)
#pragma unroll
        for (int ct = 0; ct < 2; ++ct) acc[rt][ct] = (f32x4){0.f, 0.f, 0.f, 0.f};

#pragma unroll
    for (int kt = 0; kt < 4; ++kt) {
        const int kk = kt * 32 + koff;
        short8 af[4], bf[2];
#pragma unroll
        for (int rt = 0; rt < 4; ++rt) {
            int r = row_base + rt * 16 + lr;
            r = r < nrows ? r : nrows - 1;          // clamp stays inside this block's tail
            af[rt] = ld_frag(A1 + (long)r * HD + kk);
        }
#pragma unroll
        for (int ct = 0; ct < 2; ++ct) {
            int c = col_base + ct * 16 + lr;
            bf[ct] = ld_frag(Wt1 + (long)c * HD + kk);
        }
#pragma unroll
        for (int rt = 0; rt < 4; ++rt)
#pragma unroll
            for (int ct = 0; ct < 2; ++ct)
                acc[rt][ct] = __builtin_amdgcn_mfma_f32_16x16x32_bf16(af[rt], bf[ct], acc[rt][ct], 0, 0, 0);

        if constexpr (DUAL) {
            short8 af2[4], bf2[2];
#pragma unroll
            for (int rt = 0; rt < 4; ++rt) {
                int r = row_base + rt * 16 + lr;
                r = r < nrows ? r : nrows - 1;
                af2[rt] = ld_frag(A2 + (long)r * HD + kk);
            }
#pragma unroll
            for (int ct = 0; ct < 2; ++ct) {
                int c = col_base + ct * 16 + lr;
                bf2[ct] = ld_frag(Wt2 + (long)c * HD + kk);
            }
#pragma unroll
            for (int rt = 0; rt < 4; ++rt)
#pragma unroll
                for (int ct = 0; ct < 2; ++ct)
                    acc[rt][ct] = __builtin_amdgcn_mfma_f32_16x16x32_bf16(af2[rt], bf2[ct], acc[rt][ct], 0, 0, 0);
        }
    }

    // epilogue: D layout col=lane&15, row=(lane>>4)*4+i  [m89-verified]
    float bv[2] = { bias[col_base + lr], bias[col_base + 16 + lr] };
#pragma unroll
    for (int rt = 0; rt < 4; ++rt) {
#pragma unroll
        for (int ct = 0; ct < 2; ++ct) {
            const int c = col_base + ct * 16 + lr;
#pragma unroll
            for (int i = 0; i < 4; ++i) {
                int r = row_base + rt * 16 + lg * 4 + i;
                if (r < nrows) {
                    float v = acc[rt][ct][i] + bv[ct];
                    if constexpr (RELU) v = fmaxf(v, 0.f);
                    if constexpr (F32OUT) ((float*)Cout)[(long)r * NCOL + c] = v;
                    else ((unsigned short*)Cout)[(long)r * NCOL + c] = f2bf(v);
                }
            }
        }
    }
}

// ---- prep: cast x fp32 -> bf16 (vectorized) ----
__global__ void k_cast_bf16(const float* __restrict__ in, unsigned short* __restrict__ out, long n8) {
    long i = (long)blockIdx.x * 256 + threadIdx.x;
    if (i >= n8) return;
    const float4 v0 = *((const float4*)in + i * 2);
    const float4 v1 = *((const float4*)in + i * 2 + 1);
    unsigned o[4];
    o[0] = (unsigned)f2bf(v0.x) | ((unsigned)f2bf(v0.y) << 16);
    o[1] = (unsigned)f2bf(v0.z) | ((unsigned)f2bf(v0.w) << 16);
    o[2] = (unsigned)f2bf(v1.x) | ((unsigned)f2bf(v1.y) << 16);
    o[3] = (unsigned)f2bf(v1.z) | ((unsigned)f2bf(v1.w) << 16);
    *(uint4*)(out + i * 8) = *(uint4*)o;
}

// ---- prep: cast + transpose all weight matrices into Wt[m][c][k] bf16 ----
// m: 0-2 W_lin, 3-5 W_msg(top 128 rows), 6-8 W_l, 9-11 W_r, 12 W_dec, 13 W_fin(C=64)
__global__ void k_prep_w(const float* __restrict__ Wlin, const float* __restrict__ Wmsg,
                         const float* __restrict__ Wl,   const float* __restrict__ Wr,
                         const float* __restrict__ Wdec, const float* __restrict__ Wfin,
                         unsigned short* __restrict__ wt)
{
    const int m = blockIdx.y;
    const float* src; int C = 128;
    if      (m < 3)  src = Wlin + m * 16384;
    else if (m < 6)  src = Wmsg + (m - 3) * (129 * 128);
    else if (m < 9)  src = Wl   + (m - 6) * 16384;
    else if (m < 12) src = Wr   + (m - 9) * 16384;
    else if (m == 12) src = Wdec;
    else { src = Wfin; C = 64; }
    const int elems = C * 128;
    int e = blockIdx.x * 256 + threadIdx.x;
    if (e >= elems) return;
    int c = e >> 7, k = e & 127;
    wt[m * 16384 + e] = f2bf(src[k * C + c]);
}

// ---- CSR build ----
__global__ void k_deg(const int* __restrict__ src, const int* __restrict__ dst,
                      int* __restrict__ deg, int nE, int n) {
    int e = blockIdx.x * 256 + threadIdx.x;
    if (e >= nE) return;
    unsigned d = (unsigned)dst[e], s = (unsigned)src[e];
    if (d < (unsigned)n && s < (unsigned)n) atomicAdd(&deg[d], 1);
}

__global__ void k_invdeg(const int* __restrict__ deg, float* __restrict__ inv_deg, int n) {
    int i = blockIdx.x * 256 + threadIdx.x;
    if (i < n) inv_deg[i] = 1.0f / fmaxf((float)deg[i], 1.0f);
}

__global__ void k_chunksum(const int* __restrict__ deg, int* __restrict__ csum, int n) {
    __shared__ int s[256];
    int t = threadIdx.x, i = blockIdx.x * 256 + t;
    s[t] = (i < n) ? deg[i] : 0;
    __syncthreads();
    for (int o = 128; o > 0; o >>= 1) { if (t < o) s[t] += s[t + o]; __syncthreads(); }
    if (t == 0) csum[blockIdx.x] = s[0];
}

__global__ void k_scanmid(const int* __restrict__ csum, int* __restrict__ cbase,
                          int* __restrict__ rowstart, int nch, int n) {
    __shared__ int s[512];
    int t = threadIdx.x;
    int v = (t < nch) ? csum[t] : 0;
    s[t] = v; __syncthreads();
    for (int off = 1; off < 512; off <<= 1) {
        int tmp = (t >= off) ? s[t - off] : 0;
        __syncthreads();
        s[t] += tmp;
        __syncthreads();
    }
    if (t < nch) cbase[t] = s[t] - v;
    if (t == nch - 1) rowstart[n] = s[t];
}

__global__ void k_scan2(const int* __restrict__ deg, const int* __restrict__ cbase,
                        int* __restrict__ rowstart, int n) {
    __shared__ int s[256];
    int t = threadIdx.x, i = blockIdx.x * 256 + t;
    int v = (i < n) ? deg[i] : 0;
    s[t] = v; __syncthreads();
    for (int off = 1; off < 256; off <<= 1) {
        int tmp = (t >= off) ? s[t - off] : 0;
        __syncthreads();
        s[t] += tmp;
        __syncthreads();
    }
    if (i < n) rowstart[i] = cbase[blockIdx.x] + s[t] - v;
}

__global__ void k_fill(const int* __restrict__ src, const int* __restrict__ dst,
                       const float* __restrict__ eattr, const int* __restrict__ rowstart,
                       int* __restrict__ cursor, int* __restrict__ csr_src,
                       float* __restrict__ csr_attr, int nE, int n) {
    int e = blockIdx.x * 256 + threadIdx.x;
    if (e >= nE) return;
    unsigned d = (unsigned)dst[e], s = (unsigned)src[e];
    if (d < (unsigned)n && s < (unsigned)n) {
        int p = rowstart[d] + atomicAdd(&cursor[d], 1);
        csr_src[p] = (int)s;
        csr_attr[p] = eattr[e];
    }
}

// agg[i] = bf16( inv_deg[i] * sum_p relu(g[src_p] + attr_p * wlast) ), g bf16
__global__ __launch_bounds__(256)
void k_agg(const unsigned short* __restrict__ g, const int* __restrict__ cs,
           const float* __restrict__ ca, const int* __restrict__ rs,
           const float* __restrict__ inv_deg, const float* __restrict__ wlast,
           unsigned short* __restrict__ agg, int n) {
    const int lane = threadIdx.x & 31;
    const int node = blockIdx.x * 8 + (threadIdx.x >> 5);
    if (node >= n) return;
    const int c0 = lane * 4;
    const float4 wl = *(const float4*)(wlast + c0);
    const int p0 = rs[node], p1 = rs[node + 1];
    float a0 = 0.f, a1 = 0.f, a2 = 0.f, a3 = 0.f;
    for (int p = p0; p < p1; ++p) {
        const int s = cs[p];
        const float a = ca[p];
        const uint2 gv = *(const uint2*)(g + (long)s * HD + c0);
        a0 += fmaxf(fmaf(a, wl.x, bflo(gv.x)), 0.f);
        a1 += fmaxf(fmaf(a, wl.y, bfhi(gv.x)), 0.f);
        a2 += fmaxf(fmaf(a, wl.z, bflo(gv.y)), 0.f);
        a3 += fmaxf(fmaf(a, wl.w, bfhi(gv.y)), 0.f);
    }
    const float id = inv_deg[node];
    uint2 o;
    o.x = (unsigned)f2bf(a0 * id) | ((unsigned)f2bf(a1 * id) << 16);
    o.y = (unsigned)f2bf(a2 * id) | ((unsigned)f2bf(a3 * id) << 16);
    *(uint2*)(agg + (long)node * HD + c0) = o;
}

extern "C" void kernel_launch(void* const* d_in, const int* in_sizes, int n_in,
                              void* d_out, int out_size, void* d_ws, size_t ws_size,
                              hipStream_t stream)
{
    const float* x     = (const float*)d_in[0];
    const float* eattr = (const float*)d_in[1];
    const float* W_lin = (const float*)d_in[2];
    const float* b_lin = (const float*)d_in[3];
    const float* W_msg = (const float*)d_in[4];
    const float* b_msg = (const float*)d_in[5];
    const float* W_l   = (const float*)d_in[6];
    const float* b_l   = (const float*)d_in[7];
    const float* W_r   = (const float*)d_in[8];
    const float* W_dec = (const float*)d_in[9];
    const float* b_dec = (const float*)d_in[10];
    const float* W_fin = (const float*)d_in[11];
    const float* b_fin = (const float*)d_in[12];
    const int*   ei    = (const int*)d_in[13];

    const int N = in_sizes[0] / HD;   // 100000
    const int E = in_sizes[1];        // 600000
    const int* srcv = ei;
    const int* dstv = ei + E;

    char* wsb = (char*)d_ws;
    size_t off = 0;
    auto carve = [&](size_t bytes) -> void* {
        void* p = wsb + off;
        off += (bytes + 255) & ~(size_t)255;
        return p;
    };
    unsigned short* xb = (unsigned short*)carve((size_t)N * HD * 2);
    unsigned short* t1 = (unsigned short*)carve((size_t)N * HD * 2);
    unsigned short* t2 = (unsigned short*)carve((size_t)N * HD * 2);
    unsigned short* t3 = (unsigned short*)carve((size_t)N * HD * 2);
    unsigned short* wt = (unsigned short*)carve((size_t)14 * 16384 * 2);
    int*   csr_src  = (int*)carve((size_t)E * 4);
    float* csr_attr = (float*)carve((size_t)E * 4);
    int*   rowstart = (int*)carve((size_t)(N + 1) * 4);
    int*   deg      = (int*)carve((size_t)N * 4);
    int*   cursor   = (int*)carve((size_t)N * 4);
    float* inv_deg  = (float*)carve((size_t)N * 4);
    const int NCH = (N + 255) / 256;
    int* csum  = (int*)carve((size_t)NCH * 4);
    int* cbase = (int*)carve((size_t)NCH * 4);

    if (off > ws_size) {
        hipMemsetAsync(d_out, 0, (size_t)out_size * 4, stream);
        return;
    }

    hipMemsetAsync(deg, 0, (size_t)N * 4, stream);
    hipMemsetAsync(cursor, 0, (size_t)N * 4, stream);

    // prep
    k_cast_bf16<<<(int)(((long)N * HD / 8 + 255) / 256), 256, 0, stream>>>(x, xb, (long)N * HD / 8);
    k_prep_w<<<dim3(64, 14), 256, 0, stream>>>(W_lin, W_msg, W_l, W_r, W_dec, W_fin, wt);

    // CSR
    k_deg<<<(E + 255) / 256, 256, 0, stream>>>(srcv, dstv, deg, E, N);
    k_invdeg<<<(N + 255) / 256, 256, 0, stream>>>(deg, inv_deg, N);
    k_chunksum<<<NCH, 256, 0, stream>>>(deg, csum, N);
    k_scanmid<<<1, 512, 0, stream>>>(csum, cbase, rowstart, NCH, N);
    k_scan2<<<NCH, 256, 0, stream>>>(deg, cbase, rowstart, N);
    k_fill<<<(E + 255) / 256, 256, 0, stream>>>(srcv, dstv, eattr, rowstart, cursor,
                                                csr_src, csr_attr, E, N);

    auto WT = [&](int m) { return wt + (size_t)m * 16384; };
    const int GB128 = (N + 63) / 64;    // NCOL=128 GEMMs: 64 rows/block
    const int GB64  = (N + 127) / 128;  // NCOL=64 GEMM: 128 rows/block
    const int GAGG  = (N + 7) / 8;

    // layer buffer rotation: g-buffer alternates t2/t3; output of dual == g-buffer (dead)
    const unsigned short* xin = xb;
    for (int l = 0; l < 3; ++l) {
        unsigned short* gbuf = (l & 1) ? t3 : ((l == 0) ? t2 : t2);
        // l=0: g->t2, out->t2 ; l=1: g->t3, out->t3 ; l=2: g->t2, out->t2
        unsigned short* gb = (l == 1) ? t3 : t2;
        (void)gbuf;
        // h = relu(x @ W_lin + b_lin)         -> t1
        k_mm<128, true, false, false><<<GB128, 256, 0, stream>>>(
            xin, WT(l), nullptr, nullptr, b_lin + l * HD, t1, N);
        // g = h @ Wmsg_top + b_msg            -> gb
        k_mm<128, false, false, false><<<GB128, 256, 0, stream>>>(
            t1, WT(3 + l), nullptr, nullptr, b_msg + l * HD, gb, N);
        // agg = inv_deg * sum relu(g[src] + attr*wlast)  -> t1 (h dead)
        k_agg<<<GAGG, 256, 0, stream>>>(
            gb, csr_src, csr_attr, rowstart, inv_deg,
            W_msg + (size_t)l * (HD + 1) * HD + (size_t)HD * HD, t1, N);
        // x' = relu(agg @ W_l + b_l + x @ W_r) -> gb (g dead)
        k_mm<128, true, true, false><<<GB128, 256, 0, stream>>>(
            t1, WT(6 + l), xin, WT(9 + l), b_l + l * HD, gb, N);
        xin = gb;
    }
    // emb = relu(x @ W_dec + b_dec) -> t1
    k_mm<128, true, false, false><<<GB128, 256, 0, stream>>>(
        xin, WT(12), nullptr, nullptr, b_dec, t1, N);
    // logits = emb @ W_fin + b_fin -> d_out (f32)
    k_mm<64, false, false, true><<<GB64, 256, 0, stream>>>(
        t1, WT(13), nullptr, nullptr, b_fin, (float*)d_out, N);
}

// Round 3
// 576.050 us; speedup vs baseline: 1.5971x; 1.0353x over previous
//
#include <hip/hip_runtime.h>

using short8 = __attribute__((ext_vector_type(8))) short;
using f32x4  = __attribute__((ext_vector_type(4))) float;

constexpr int HD = 128;

__device__ __forceinline__ unsigned short f2bf(float f) {
    unsigned u = __builtin_bit_cast(unsigned, f);
    u += 0x7fffu + ((u >> 16) & 1u);          // round-to-nearest-even
    return (unsigned short)(u >> 16);
}
__device__ __forceinline__ float bflo(unsigned u) { return __builtin_bit_cast(float, u << 16); }
__device__ __forceinline__ float bfhi(unsigned u) { return __builtin_bit_cast(float, u & 0xffff0000u); }

__device__ __forceinline__ short8 ldg8(const unsigned short* p) {
    return *reinterpret_cast<const short8*>(p);   // 16B contiguous, aligned
}

// ---------------------------------------------------------------------------
// Fused back-to-back GEMM: Out = (relu(A @ Wt1 + b1)) @ Wt2 + b2
// A: [nrows][128] bf16. Wt: [NCOL][128] bf16 (pre-transposed). Block: 32 rows.
// Phase 1 (NCOL=128): wave w computes cols w*32..w*32+31, h-tile -> LDS
// (16B-slot XOR swizzle so phase-2 ds_read_b128 is bank-uniform).
// Phase 2 (NC2 cols): A-frags from LDS, B from global (L2-hot).
// All global fragment loads are issued up front (independent) for MLP.
// k-slot permutation (lane>>4)*8 applied identically to A and B: MFMA-invariant.
// ---------------------------------------------------------------------------
template<int NC2, bool F32OUT>
__global__ __launch_bounds__(256, 4)
void k_fused2(const unsigned short* __restrict__ A, const unsigned short* __restrict__ Wt1,
              const float* __restrict__ b1, const unsigned short* __restrict__ Wt2,
              const float* __restrict__ b2, void* __restrict__ Out, int nrows)
{
    __shared__ unsigned short hl[32 * HD];
    const int lane = threadIdx.x & 63;
    const int wave = threadIdx.x >> 6;
    const int lr = lane & 15, lg = lane >> 4;
    const int koff = lg * 8;
    const int row0 = blockIdx.x * 32;

    // ---- phase 1: h = relu(A @ Wt1 + b1), 32 rows x 128 cols ----
    const int cb1 = wave * 32;
    short8 af[2][4], bf[2][4];
#pragma unroll
    for (int rt = 0; rt < 2; ++rt) {
        int r = row0 + rt * 16 + lr; r = r < nrows ? r : nrows - 1;
        const unsigned short* ap = A + (long)r * HD + koff;
#pragma unroll
        for (int kt = 0; kt < 4; ++kt) af[rt][kt] = ldg8(ap + kt * 32);
    }
#pragma unroll
    for (int ct = 0; ct < 2; ++ct) {
        const unsigned short* bp = Wt1 + (long)(cb1 + ct * 16 + lr) * HD + koff;
#pragma unroll
        for (int kt = 0; kt < 4; ++kt) bf[ct][kt] = ldg8(bp + kt * 32);
    }
    f32x4 acc[2][2] = {};
#pragma unroll
    for (int kt = 0; kt < 4; ++kt)
#pragma unroll
        for (int rt = 0; rt < 2; ++rt)
#pragma unroll
            for (int ct = 0; ct < 2; ++ct)
                acc[rt][ct] = __builtin_amdgcn_mfma_f32_16x16x32_bf16(af[rt][kt], bf[ct][kt], acc[rt][ct], 0, 0, 0);

    const float bv1[2] = { b1[cb1 + lr], b1[cb1 + 16 + lr] };
#pragma unroll
    for (int rt = 0; rt < 2; ++rt)
#pragma unroll
        for (int ct = 0; ct < 2; ++ct) {
            const int c = cb1 + ct * 16 + lr;
#pragma unroll
            for (int i = 0; i < 4; ++i) {
                const int rl = rt * 16 + lg * 4 + i;
                const float v = fmaxf(acc[rt][ct][i] + bv1[ct], 0.f);
                hl[rl * HD + ((((c >> 3) ^ (rl & 7)) << 3) | (c & 7))] = f2bf(v);
            }
        }
    __syncthreads();

    // ---- phase 2: Out = h @ Wt2 + b2 (no relu) ----
    constexpr int CT2 = NC2 / 64;            // coltiles per wave: 2 (NC2=128) or 1 (64)
    const int cb2 = wave * (NC2 / 4);
    short8 ah[2][4];
#pragma unroll
    for (int rt = 0; rt < 2; ++rt) {
        const int rl = rt * 16 + lr;
#pragma unroll
        for (int kt = 0; kt < 4; ++kt) {
            const int slot = kt * 4 + lg;
            ah[rt][kt] = *reinterpret_cast<const short8*>(&hl[rl * HD + ((slot ^ (rl & 7)) << 3)]);
        }
    }
    short8 bh[CT2][4];
#pragma unroll
    for (int ct = 0; ct < CT2; ++ct) {
        const unsigned short* bp = Wt2 + (long)(cb2 + ct * 16 + lr) * HD + koff;
#pragma unroll
        for (int kt = 0; kt < 4; ++kt) bh[ct][kt] = ldg8(bp + kt * 32);
    }
    f32x4 acc2[2][CT2] = {};
#pragma unroll
    for (int kt = 0; kt < 4; ++kt)
#pragma unroll
        for (int rt = 0; rt < 2; ++rt)
#pragma unroll
            for (int ct = 0; ct < CT2; ++ct)
                acc2[rt][ct] = __builtin_amdgcn_mfma_f32_16x16x32_bf16(ah[rt][kt], bh[ct][kt], acc2[rt][ct], 0, 0, 0);

    float bv2[CT2];
#pragma unroll
    for (int ct = 0; ct < CT2; ++ct) bv2[ct] = b2[cb2 + ct * 16 + lr];
#pragma unroll
    for (int rt = 0; rt < 2; ++rt)
#pragma unroll
        for (int ct = 0; ct < CT2; ++ct) {
            const int c = cb2 + ct * 16 + lr;
#pragma unroll
            for (int i = 0; i < 4; ++i) {
                const int r = row0 + rt * 16 + lg * 4 + i;
                if (r < nrows) {
                    const float v = acc2[rt][ct][i] + bv2[ct];
                    if constexpr (F32OUT) ((float*)Out)[(long)r * NC2 + c] = v;
                    else ((unsigned short*)Out)[(long)r * NC2 + c] = f2bf(v);
                }
            }
        }
}

// ---------------------------------------------------------------------------
// Dual GEMM: C = relu(A1 @ Wt1 + A2 @ Wt2 + bias), all [nrows][128] bf16.
// Wave: 32 rows x 16 cols; block: 32 rows x 64 cols; 24 loads in flight/wave.
// ---------------------------------------------------------------------------
__global__ __launch_bounds__(256, 4)
void k_dual(const unsigned short* __restrict__ A1, const unsigned short* __restrict__ Wt1,
            const unsigned short* __restrict__ A2, const unsigned short* __restrict__ Wt2,
            const float* __restrict__ bias, unsigned short* __restrict__ C, int nrows)
{
    const int lane = threadIdx.x & 63, wave = threadIdx.x >> 6;
    const int lr = lane & 15, lg = lane >> 4, koff = lg * 8;
    const int row0 = (blockIdx.x >> 1) * 32;
    const int c0 = (blockIdx.x & 1) * 64 + wave * 16;

    short8 a1[2][4], a2[2][4], b1[4], b2[4];
#pragma unroll
    for (int rt = 0; rt < 2; ++rt) {
        int r = row0 + rt * 16 + lr; r = r < nrows ? r : nrows - 1;
        const unsigned short* p1 = A1 + (long)r * HD + koff;
        const unsigned short* p2 = A2 + (long)r * HD + koff;
#pragma unroll
        for (int kt = 0; kt < 4; ++kt) { a1[rt][kt] = ldg8(p1 + kt * 32); a2[rt][kt] = ldg8(p2 + kt * 32); }
    }
    {
        const unsigned short* q1 = Wt1 + (long)(c0 + lr) * HD + koff;
        const unsigned short* q2 = Wt2 + (long)(c0 + lr) * HD + koff;
#pragma unroll
        for (int kt = 0; kt < 4; ++kt) { b1[kt] = ldg8(q1 + kt * 32); b2[kt] = ldg8(q2 + kt * 32); }
    }
    f32x4 acc[2] = {};
#pragma unroll
    for (int kt = 0; kt < 4; ++kt)
#pragma unroll
        for (int rt = 0; rt < 2; ++rt) {
            acc[rt] = __builtin_amdgcn_mfma_f32_16x16x32_bf16(a1[rt][kt], b1[kt], acc[rt], 0, 0, 0);
            acc[rt] = __builtin_amdgcn_mfma_f32_16x16x32_bf16(a2[rt][kt], b2[kt], acc[rt], 0, 0, 0);
        }
    const float bv = bias[c0 + lr];
#pragma unroll
    for (int rt = 0; rt < 2; ++rt)
#pragma unroll
        for (int i = 0; i < 4; ++i) {
            const int r = row0 + rt * 16 + lg * 4 + i;
            if (r < nrows) C[(long)r * HD + c0 + lr] = f2bf(fmaxf(acc[rt][i] + bv, 0.f));
        }
}

// ---- prep: cast x fp32 -> bf16 (vectorized) ----
__global__ void k_cast_bf16(const float* __restrict__ in, unsigned short* __restrict__ out, long n8) {
    long i = (long)blockIdx.x * 256 + threadIdx.x;
    if (i >= n8) return;
    const float4 v0 = *((const float4*)in + i * 2);
    const float4 v1 = *((const float4*)in + i * 2 + 1);
    unsigned o[4];
    o[0] = (unsigned)f2bf(v0.x) | ((unsigned)f2bf(v0.y) << 16);
    o[1] = (unsigned)f2bf(v0.z) | ((unsigned)f2bf(v0.w) << 16);
    o[2] = (unsigned)f2bf(v1.x) | ((unsigned)f2bf(v1.y) << 16);
    o[3] = (unsigned)f2bf(v1.z) | ((unsigned)f2bf(v1.w) << 16);
    *(uint4*)(out + i * 8) = *(uint4*)o;
}

// ---- prep: cast + transpose weights into wt[m][c][k] bf16 ----
// m: 0-2 W_lin, 3-5 W_msg(top 128), 6-8 W_l, 9-11 W_r, 12 W_dec, 13 W_fin(C=64)
__global__ void k_prep_w(const float* __restrict__ Wlin, const float* __restrict__ Wmsg,
                         const float* __restrict__ Wl,   const float* __restrict__ Wr,
                         const float* __restrict__ Wdec, const float* __restrict__ Wfin,
                         unsigned short* __restrict__ wt)
{
    const int m = blockIdx.y;
    const float* src; int C = 128;
    if      (m < 3)  src = Wlin + m * 16384;
    else if (m < 6)  src = Wmsg + (m - 3) * (129 * 128);
    else if (m < 9)  src = Wl   + (m - 6) * 16384;
    else if (m < 12) src = Wr   + (m - 9) * 16384;
    else if (m == 12) src = Wdec;
    else { src = Wfin; C = 64; }
    const int elems = C * 128;
    int e = blockIdx.x * 256 + threadIdx.x;
    if (e >= elems) return;
    int c = e >> 7, k = e & 127;
    wt[m * 16384 + e] = f2bf(src[k * C + c]);
}

// ---- CSR build ----
__global__ void k_deg(const int* __restrict__ src, const int* __restrict__ dst,
                      int* __restrict__ deg, int nE, int n) {
    int e = blockIdx.x * 256 + threadIdx.x;
    if (e >= nE) return;
    unsigned d = (unsigned)dst[e], s = (unsigned)src[e];
    if (d < (unsigned)n && s < (unsigned)n) atomicAdd(&deg[d], 1);
}

__global__ void k_invdeg(const int* __restrict__ deg, float* __restrict__ inv_deg, int n) {
    int i = blockIdx.x * 256 + threadIdx.x;
    if (i < n) inv_deg[i] = 1.0f / fmaxf((float)deg[i], 1.0f);
}

__global__ void k_chunksum(const int* __restrict__ deg, int* __restrict__ csum, int n) {
    __shared__ int s[256];
    int t = threadIdx.x, i = blockIdx.x * 256 + t;
    s[t] = (i < n) ? deg[i] : 0;
    __syncthreads();
    for (int o = 128; o > 0; o >>= 1) { if (t < o) s[t] += s[t + o]; __syncthreads(); }
    if (t == 0) csum[blockIdx.x] = s[0];
}

__global__ void k_scanmid(const int* __restrict__ csum, int* __restrict__ cbase,
                          int* __restrict__ rowstart, int nch, int n) {
    __shared__ int s[512];
    int t = threadIdx.x;
    int v = (t < nch) ? csum[t] : 0;
    s[t] = v; __syncthreads();
    for (int off = 1; off < 512; off <<= 1) {
        int tmp = (t >= off) ? s[t - off] : 0;
        __syncthreads();
        s[t] += tmp;
        __syncthreads();
    }
    if (t < nch) cbase[t] = s[t] - v;
    if (t == nch - 1) rowstart[n] = s[t];
}

__global__ void k_scan2(const int* __restrict__ deg, const int* __restrict__ cbase,
                        int* __restrict__ rowstart, int n) {
    __shared__ int s[256];
    int t = threadIdx.x, i = blockIdx.x * 256 + t;
    int v = (i < n) ? deg[i] : 0;
    s[t] = v; __syncthreads();
    for (int off = 1; off < 256; off <<= 1) {
        int tmp = (t >= off) ? s[t - off] : 0;
        __syncthreads();
        s[t] += tmp;
        __syncthreads();
    }
    if (i < n) rowstart[i] = cbase[blockIdx.x] + s[t] - v;
}

__global__ void k_fill(const int* __restrict__ src, const int* __restrict__ dst,
                       const float* __restrict__ eattr, const int* __restrict__ rowstart,
                       int* __restrict__ cursor, int* __restrict__ csr_src,
                       float* __restrict__ csr_attr, int nE, int n) {
    int e = blockIdx.x * 256 + threadIdx.x;
    if (e >= nE) return;
    unsigned d = (unsigned)dst[e], s = (unsigned)src[e];
    if (d < (unsigned)n && s < (unsigned)n) {
        int p = rowstart[d] + atomicAdd(&cursor[d], 1);
        csr_src[p] = (int)s;
        csr_attr[p] = eattr[e];
    }
}

// agg[i] = bf16( inv_deg[i] * sum_p relu(g[src_p] + attr_p * wlast) ), 2-edge unroll
__global__ __launch_bounds__(256)
void k_agg(const unsigned short* __restrict__ g, const int* __restrict__ cs,
           const float* __restrict__ ca, const int* __restrict__ rs,
           const float* __restrict__ inv_deg, const float* __restrict__ wlast,
           unsigned short* __restrict__ agg, int n) {
    const int lane = threadIdx.x & 31;
    const int node = blockIdx.x * 8 + (threadIdx.x >> 5);
    if (node >= n) return;
    const int c0 = lane * 4;
    const float4 wl = *(const float4*)(wlast + c0);
    const int p0 = rs[node], p1 = rs[node + 1];
    float a0 = 0.f, a1 = 0.f, a2 = 0.f, a3 = 0.f;
    int p = p0;
    for (; p + 2 <= p1; p += 2) {
        const int s0 = cs[p], s1 = cs[p + 1];
        const float e0 = ca[p], e1 = ca[p + 1];
        const uint2 g0 = *(const uint2*)(g + (long)s0 * HD + c0);
        const uint2 g1 = *(const uint2*)(g + (long)s1 * HD + c0);
        a0 += fmaxf(fmaf(e0, wl.x, bflo(g0.x)), 0.f) + fmaxf(fmaf(e1, wl.x, bflo(g1.x)), 0.f);
        a1 += fmaxf(fmaf(e0, wl.y, bfhi(g0.x)), 0.f) + fmaxf(fmaf(e1, wl.y, bfhi(g1.x)), 0.f);
        a2 += fmaxf(fmaf(e0, wl.z, bflo(g0.y)), 0.f) + fmaxf(fmaf(e1, wl.z, bflo(g1.y)), 0.f);
        a3 += fmaxf(fmaf(e0, wl.w, bfhi(g0.y)), 0.f) + fmaxf(fmaf(e1, wl.w, bfhi(g1.y)), 0.f);
    }
    if (p < p1) {
        const int s0 = cs[p];
        const float e0 = ca[p];
        const uint2 g0 = *(const uint2*)(g + (long)s0 * HD + c0);
        a0 += fmaxf(fmaf(e0, wl.x, bflo(g0.x)), 0.f);
        a1 += fmaxf(fmaf(e0, wl.y, bfhi(g0.x)), 0.f);
        a2 += fmaxf(fmaf(e0, wl.z, bflo(g0.y)), 0.f);
        a3 += fmaxf(fmaf(e0, wl.w, bfhi(g0.y)), 0.f);
    }
    const float id = inv_deg[node];
    uint2 o;
    o.x = (unsigned)f2bf(a0 * id) | ((unsigned)f2bf(a1 * id) << 16);
    o.y = (unsigned)f2bf(a2 * id) | ((unsigned)f2bf(a3 * id) << 16);
    *(uint2*)(agg + (long)node * HD + c0) = o;
}

extern "C" void kernel_launch(void* const* d_in, const int* in_sizes, int n_in,
                              void* d_out, int out_size, void* d_ws, size_t ws_size,
                              hipStream_t stream)
{
    const float* x     = (const float*)d_in[0];
    const float* eattr = (const float*)d_in[1];
    const float* W_lin = (const float*)d_in[2];
    const float* b_lin = (const float*)d_in[3];
    const float* W_msg = (const float*)d_in[4];
    const float* b_msg = (const float*)d_in[5];
    const float* W_l   = (const float*)d_in[6];
    const float* b_l   = (const float*)d_in[7];
    const float* W_r   = (const float*)d_in[8];
    const float* W_dec = (const float*)d_in[9];
    const float* b_dec = (const float*)d_in[10];
    const float* W_fin = (const float*)d_in[11];
    const float* b_fin = (const float*)d_in[12];
    const int*   ei    = (const int*)d_in[13];

    const int N = in_sizes[0] / HD;   // 100000
    const int E = in_sizes[1];        // 600000
    const int* srcv = ei;
    const int* dstv = ei + E;

    char* wsb = (char*)d_ws;
    size_t off = 0;
    auto carve = [&](size_t bytes) -> void* {
        void* p = wsb + off;
        off += (bytes + 255) & ~(size_t)255;
        return p;
    };
    unsigned short* xb = (unsigned short*)carve((size_t)N * HD * 2);
    unsigned short* t1 = (unsigned short*)carve((size_t)N * HD * 2);
    unsigned short* t2 = (unsigned short*)carve((size_t)N * HD * 2);
    unsigned short* t3 = (unsigned short*)carve((size_t)N * HD * 2);
    unsigned short* wt = (unsigned short*)carve((size_t)14 * 16384 * 2);
    int*   csr_src  = (int*)carve((size_t)E * 4);
    float* csr_attr = (float*)carve((size_t)E * 4);
    int*   rowstart = (int*)carve((size_t)(N + 1) * 4);
    int*   deg      = (int*)carve((size_t)N * 4);
    int*   cursor   = (int*)carve((size_t)N * 4);
    float* inv_deg  = (float*)carve((size_t)N * 4);
    const int NCH = (N + 255) / 256;
    int* csum  = (int*)carve((size_t)NCH * 4);
    int* cbase = (int*)carve((size_t)NCH * 4);

    if (off > ws_size) {
        hipMemsetAsync(d_out, 0, (size_t)out_size * 4, stream);
        return;
    }

    hipMemsetAsync(deg, 0, (size_t)N * 4, stream);
    hipMemsetAsync(cursor, 0, (size_t)N * 4, stream);

    // prep
    k_cast_bf16<<<(int)(((long)N * HD / 8 + 255) / 256), 256, 0, stream>>>(x, xb, (long)N * HD / 8);
    k_prep_w<<<dim3(64, 14), 256, 0, stream>>>(W_lin, W_msg, W_l, W_r, W_dec, W_fin, wt);

    // CSR
    k_deg<<<(E + 255) / 256, 256, 0, stream>>>(srcv, dstv, deg, E, N);
    k_invdeg<<<(N + 255) / 256, 256, 0, stream>>>(deg, inv_deg, N);
    k_chunksum<<<NCH, 256, 0, stream>>>(deg, csum, N);
    k_scanmid<<<1, 512, 0, stream>>>(csum, cbase, rowstart, NCH, N);
    k_scan2<<<NCH, 256, 0, stream>>>(deg, cbase, rowstart, N);
    k_fill<<<(E + 255) / 256, 256, 0, stream>>>(srcv, dstv, eattr, rowstart, cursor,
                                                csr_src, csr_attr, E, N);

    auto WT = [&](int m) { return wt + (size_t)m * 16384; };
    const int NB32 = (N + 31) / 32;
    const int GAGG = (N + 7) / 8;

    const unsigned short* xin = xb;
    for (int l = 0; l < 3; ++l) {
        unsigned short* gb = (l == 1) ? t3 : t2;   // xin rotates xb -> t2 -> t3 -> t2
        // g = relu(x @ W_lin + b_lin) @ Wmsg_top + b_msg   (h stays in LDS)
        k_fused2<128, false><<<NB32, 256, 0, stream>>>(
            xin, WT(l), b_lin + l * HD, WT(3 + l), b_msg + l * HD, gb, N);
        // agg = inv_deg * sum relu(g[src] + attr*wlast)  -> t1
        k_agg<<<GAGG, 256, 0, stream>>>(
            gb, csr_src, csr_attr, rowstart, inv_deg,
            W_msg + (size_t)l * (HD + 1) * HD + (size_t)HD * HD, t1, N);
        // x' = relu(agg @ W_l + x @ W_r + b_l) -> gb (g dead; gb != xin)
        k_dual<<<NB32 * 2, 256, 0, stream>>>(
            t1, WT(6 + l), xin, WT(9 + l), b_l + l * HD, gb, N);
        xin = gb;
    }
    // logits = relu(x @ W_dec + b_dec) @ W_fin + b_fin -> d_out (f32)
    k_fused2<64, true><<<NB32, 256, 0, stream>>>(
        xin, WT(12), b_dec, WT(13), b_fin, (float*)d_out, N);
}

// Round 4
// 369.923 us; speedup vs baseline: 2.4871x; 1.5572x over previous
//
#include <hip/hip_runtime.h>

using short8 = __attribute__((ext_vector_type(8))) short;
using f32x4  = __attribute__((ext_vector_type(4))) float;

constexpr int HD = 128;

__device__ __forceinline__ unsigned short f2bf(float f) {
    unsigned u = __builtin_bit_cast(unsigned, f);
    u += 0x7fffu + ((u >> 16) & 1u);          // round-to-nearest-even
    return (unsigned short)(u >> 16);
}
__device__ __forceinline__ float bflo(unsigned u) { return __builtin_bit_cast(float, u << 16); }
__device__ __forceinline__ float bfhi(unsigned u) { return __builtin_bit_cast(float, u & 0xffff0000u); }

__device__ __forceinline__ short8 ldg8(const unsigned short* p) {
    return *reinterpret_cast<const short8*>(p);   // 16B contiguous, aligned
}

// ---------------------------------------------------------------------------
// Staged GEMM. Block = 64 rows x 128 cols, 4 waves (wave w -> cols w*32..+31).
// A-tiles stream global->LDS via async global_load_lds (16B/lane, contiguous
// 1KB per wave-instruction). Source addresses are pre-swizzled (chunk ^= row&7,
// m173 pattern) so LDS remains linear for the DMA but ds_read_b128 fragment
// reads spread across 8 bank slots. Weights are loaded to registers from L2.
//   DUAL : Out = relu(A1@Wt1 + A2@Wt2 + b1)
//   CHAIN: Out = (relu(A1@Wt1 + b1)) @ Wtc + b2   (h kept in swizzled LDS)
// ---------------------------------------------------------------------------
template<bool DUAL, bool CHAIN, int NC2, bool F32OUT>
__global__ __launch_bounds__(256)
void k_gemm_s(const unsigned short* __restrict__ A1, const unsigned short* __restrict__ Wt1,
              const unsigned short* __restrict__ A2, const unsigned short* __restrict__ Wt2,
              const unsigned short* __restrict__ Wtc, const float* __restrict__ b1,
              const float* __restrict__ b2, void* __restrict__ Out, int nrows)
{
    __shared__ __align__(16) unsigned short As1[64 * HD];
    __shared__ __align__(16) unsigned short As2[DUAL ? 64 * HD : 8];
    __shared__ __align__(16) unsigned short Hs [CHAIN ? 64 * HD : 8];

    const int tid  = threadIdx.x;
    const int lane = tid & 63, wave = tid >> 6;
    const int lr = lane & 15, lg = lane >> 4;
    const int row0 = blockIdx.x * 64;

    // ---- issue async DMA staging of A tile(s) ----
#pragma unroll
    for (int it = 0; it < 4; ++it) {
        const int q   = wave * 4 + it;          // 1KB chunk id (wave-uniform)
        const int c   = q * 64 + lane;          // 16B chunk id 0..1023
        const int row = c >> 4, cw = c & 15;    // within-tile row, chunk-in-row
        int grow = row0 + row; grow = grow < nrows ? grow : nrows - 1;
        const int gco = (cw ^ (row & 7)) << 3;  // swizzled source element offset
        __builtin_amdgcn_global_load_lds((const unsigned int*)(A1 + (long)grow * HD + gco),
                                         (unsigned int*)&As1[q * 512], 16, 0, 0);
        if constexpr (DUAL)
            __builtin_amdgcn_global_load_lds((const unsigned int*)(A2 + (long)grow * HD + gco),
                                             (unsigned int*)&As2[q * 512], 16, 0, 0);
    }

    // ---- weight fragments (L2-hot), overlap with DMA ----
    const int cb1 = wave * 32;
    short8 bf1[2][4];
#pragma unroll
    for (int ct = 0; ct < 2; ++ct) {
        const unsigned short* bp = Wt1 + (long)(cb1 + ct * 16 + lr) * HD + lg * 8;
#pragma unroll
        for (int kt = 0; kt < 4; ++kt) bf1[ct][kt] = ldg8(bp + kt * 32);
    }
    short8 bf2[DUAL ? 2 : 1][4];
    if constexpr (DUAL) {
#pragma unroll
        for (int ct = 0; ct < 2; ++ct) {
            const unsigned short* bp = Wt2 + (long)(cb1 + ct * 16 + lr) * HD + lg * 8;
#pragma unroll
            for (int kt = 0; kt < 4; ++kt) bf2[ct][kt] = ldg8(bp + kt * 32);
        }
    }
    constexpr int CT2 = CHAIN ? (NC2 / 64) : 1;
    const int cb2 = wave * (NC2 / 4);
    short8 bfc[CT2][4];
    if constexpr (CHAIN) {
#pragma unroll
        for (int ct = 0; ct < CT2; ++ct) {
            const unsigned short* bp = Wtc + (long)(cb2 + ct * 16 + lr) * HD + lg * 8;
#pragma unroll
            for (int kt = 0; kt < 4; ++kt) bfc[ct][kt] = ldg8(bp + kt * 32);
        }
    }

    __syncthreads();   // compiler drains vmcnt (DMA + weight loads) before barrier

    // ---- phase 1 MFMA: acc = A1@Wt1 [+ A2@Wt2] ----
    f32x4 acc[4][2] = {};
#pragma unroll
    for (int kt = 0; kt < 4; ++kt) {
        short8 af[4];
#pragma unroll
        for (int rt = 0; rt < 4; ++rt)
            af[rt] = *reinterpret_cast<const short8*>(
                &As1[(rt * 16 + lr) * HD + (((kt * 4 + lg) ^ (lr & 7)) << 3)]);
#pragma unroll
        for (int rt = 0; rt < 4; ++rt)
#pragma unroll
            for (int ct = 0; ct < 2; ++ct)
                acc[rt][ct] = __builtin_amdgcn_mfma_f32_16x16x32_bf16(af[rt], bf1[ct][kt], acc[rt][ct], 0, 0, 0);
        if constexpr (DUAL) {
            short8 af2[4];
#pragma unroll
            for (int rt = 0; rt < 4; ++rt)
                af2[rt] = *reinterpret_cast<const short8*>(
                    &As2[(rt * 16 + lr) * HD + (((kt * 4 + lg) ^ (lr & 7)) << 3)]);
#pragma unroll
            for (int rt = 0; rt < 4; ++rt)
#pragma unroll
                for (int ct = 0; ct < 2; ++ct)
                    acc[rt][ct] = __builtin_amdgcn_mfma_f32_16x16x32_bf16(af2[rt], bf2[ct][kt], acc[rt][ct], 0, 0, 0);
        }
    }

    const float bv1[2] = { b1[cb1 + lr], b1[cb1 + 16 + lr] };

    if constexpr (!CHAIN) {
        // relu + store bf16
        unsigned short* C = (unsigned short*)Out;
#pragma unroll
        for (int rt = 0; rt < 4; ++rt)
#pragma unroll
            for (int ct = 0; ct < 2; ++ct) {
                const int cc = cb1 + ct * 16 + lr;
#pragma unroll
                for (int i = 0; i < 4; ++i) {
                    const int r = row0 + rt * 16 + lg * 4 + i;
                    if (r < nrows) C[(long)r * HD + cc] = f2bf(fmaxf(acc[rt][ct][i] + bv1[ct], 0.f));
                }
            }
    } else {
        // h = relu(acc + b1) -> Hs (swizzled layout, same read path as As)
#pragma unroll
        for (int rt = 0; rt < 4; ++rt)
#pragma unroll
            for (int ct = 0; ct < 2; ++ct) {
                const int cc = cb1 + ct * 16 + lr;
#pragma unroll
                for (int i = 0; i < 4; ++i) {
                    const int row = rt * 16 + lg * 4 + i;
                    const float v = fmaxf(acc[rt][ct][i] + bv1[ct], 0.f);
                    Hs[row * HD + ((((cc >> 3) ^ (row & 7)) << 3) | (cc & 7))] = f2bf(v);
                }
            }
        __syncthreads();

        // ---- phase 2: Out = h @ Wtc + b2 ----
        f32x4 acc2[4][CT2] = {};
#pragma unroll
        for (int kt = 0; kt < 4; ++kt) {
            short8 ah[4];
#pragma unroll
            for (int rt = 0; rt < 4; ++rt)
                ah[rt] = *reinterpret_cast<const short8*>(
                    &Hs[(rt * 16 + lr) * HD + (((kt * 4 + lg) ^ (lr & 7)) << 3)]);
#pragma unroll
            for (int rt = 0; rt < 4; ++rt)
#pragma unroll
                for (int ct = 0; ct < CT2; ++ct)
                    acc2[rt][ct] = __builtin_amdgcn_mfma_f32_16x16x32_bf16(ah[rt], bfc[ct][kt], acc2[rt][ct], 0, 0, 0);
        }
        float bv2[CT2];
#pragma unroll
        for (int ct = 0; ct < CT2; ++ct) bv2[ct] = b2[cb2 + ct * 16 + lr];
#pragma unroll
        for (int rt = 0; rt < 4; ++rt)
#pragma unroll
            for (int ct = 0; ct < CT2; ++ct) {
                const int cc = cb2 + ct * 16 + lr;
#pragma unroll
                for (int i = 0; i < 4; ++i) {
                    const int r = row0 + rt * 16 + lg * 4 + i;
                    if (r < nrows) {
                        const float v = acc2[rt][ct][i] + bv2[ct];
                        if constexpr (F32OUT) ((float*)Out)[(long)r * NC2 + cc] = v;
                        else ((unsigned short*)Out)[(long)r * NC2 + cc] = f2bf(v);
                    }
                }
            }
    }
}

// ---- prep: cast x fp32 -> bf16 (vectorized) ----
__global__ void k_cast_bf16(const float* __restrict__ in, unsigned short* __restrict__ out, long n8) {
    long i = (long)blockIdx.x * 256 + threadIdx.x;
    if (i >= n8) return;
    const float4 v0 = *((const float4*)in + i * 2);
    const float4 v1 = *((const float4*)in + i * 2 + 1);
    unsigned o[4];
    o[0] = (unsigned)f2bf(v0.x) | ((unsigned)f2bf(v0.y) << 16);
    o[1] = (unsigned)f2bf(v0.z) | ((unsigned)f2bf(v0.w) << 16);
    o[2] = (unsigned)f2bf(v1.x) | ((unsigned)f2bf(v1.y) << 16);
    o[3] = (unsigned)f2bf(v1.z) | ((unsigned)f2bf(v1.w) << 16);
    *(uint4*)(out + i * 8) = *(uint4*)o;
}

// ---- prep: cast + transpose weights into wt[m][c][k] bf16 ----
// m: 0-2 W_lin, 3-5 W_msg(top 128), 6-8 W_l, 9-11 W_r, 12 W_dec, 13 W_fin(C=64)
__global__ void k_prep_w(const float* __restrict__ Wlin, const float* __restrict__ Wmsg,
                         const float* __restrict__ Wl,   const float* __restrict__ Wr,
                         const float* __restrict__ Wdec, const float* __restrict__ Wfin,
                         unsigned short* __restrict__ wt)
{
    const int m = blockIdx.y;
    const float* src; int C = 128;
    if      (m < 3)  src = Wlin + m * 16384;
    else if (m < 6)  src = Wmsg + (m - 3) * (129 * 128);
    else if (m < 9)  src = Wl   + (m - 6) * 16384;
    else if (m < 12) src = Wr   + (m - 9) * 16384;
    else if (m == 12) src = Wdec;
    else { src = Wfin; C = 64; }
    const int elems = C * 128;
    int e = blockIdx.x * 256 + threadIdx.x;
    if (e >= elems) return;
    int c = e >> 7, k = e & 127;
    wt[m * 16384 + e] = f2bf(src[k * C + c]);
}

// ---- CSR build ----
__global__ void k_deg(const int* __restrict__ src, const int* __restrict__ dst,
                      int* __restrict__ deg, int nE, int n) {
    int e = blockIdx.x * 256 + threadIdx.x;
    if (e >= nE) return;
    unsigned d = (unsigned)dst[e], s = (unsigned)src[e];
    if (d < (unsigned)n && s < (unsigned)n) atomicAdd(&deg[d], 1);
}

__global__ void k_invdeg(const int* __restrict__ deg, float* __restrict__ inv_deg, int n) {
    int i = blockIdx.x * 256 + threadIdx.x;
    if (i < n) inv_deg[i] = 1.0f / fmaxf((float)deg[i], 1.0f);
}

__global__ void k_chunksum(const int* __restrict__ deg, int* __restrict__ csum, int n) {
    __shared__ int s[256];
    int t = threadIdx.x, i = blockIdx.x * 256 + t;
    s[t] = (i < n) ? deg[i] : 0;
    __syncthreads();
    for (int o = 128; o > 0; o >>= 1) { if (t < o) s[t] += s[t + o]; __syncthreads(); }
    if (t == 0) csum[blockIdx.x] = s[0];
}

__global__ void k_scanmid(const int* __restrict__ csum, int* __restrict__ cbase,
                          int* __restrict__ rowstart, int nch, int n) {
    __shared__ int s[512];
    int t = threadIdx.x;
    int v = (t < nch) ? csum[t] : 0;
    s[t] = v; __syncthreads();
    for (int off = 1; off < 512; off <<= 1) {
        int tmp = (t >= off) ? s[t - off] : 0;
        __syncthreads();
        s[t] += tmp;
        __syncthreads();
    }
    if (t < nch) cbase[t] = s[t] - v;
    if (t == nch - 1) rowstart[n] = s[t];
}

__global__ void k_scan2(const int* __restrict__ deg, const int* __restrict__ cbase,
                        int* __restrict__ rowstart, int n) {
    __shared__ int s[256];
    int t = threadIdx.x, i = blockIdx.x * 256 + t;
    int v = (i < n) ? deg[i] : 0;
    s[t] = v; __syncthreads();
    for (int off = 1; off < 256; off <<= 1) {
        int tmp = (t >= off) ? s[t - off] : 0;
        __syncthreads();
        s[t] += tmp;
        __syncthreads();
    }
    if (i < n) rowstart[i] = cbase[blockIdx.x] + s[t] - v;
}

__global__ void k_fill(const int* __restrict__ src, const int* __restrict__ dst,
                       const float* __restrict__ eattr, const int* __restrict__ rowstart,
                       int* __restrict__ cursor, int* __restrict__ csr_src,
                       float* __restrict__ csr_attr, int nE, int n) {
    int e = blockIdx.x * 256 + threadIdx.x;
    if (e >= nE) return;
    unsigned d = (unsigned)dst[e], s = (unsigned)src[e];
    if (d < (unsigned)n && s < (unsigned)n) {
        int p = rowstart[d] + atomicAdd(&cursor[d], 1);
        csr_src[p] = (int)s;
        csr_attr[p] = eattr[e];
    }
}

// agg[i] = bf16( inv_deg[i] * sum_p relu(g[src_p] + attr_p * wlast) )
// 16 lanes/node, 16B/lane, 2-edge unroll.
__global__ __launch_bounds__(256)
void k_agg(const unsigned short* __restrict__ g, const int* __restrict__ cs,
           const float* __restrict__ ca, const int* __restrict__ rs,
           const float* __restrict__ inv_deg, const float* __restrict__ wlast,
           unsigned short* __restrict__ agg, int n) {
    const int lane = threadIdx.x & 15;
    const int node = blockIdx.x * 16 + (threadIdx.x >> 4);
    if (node >= n) return;
    const int c0 = lane * 8;
    const float4 wla = *(const float4*)(wlast + c0);
    const float4 wlb = *(const float4*)(wlast + c0 + 4);
    const int p0 = rs[node], p1 = rs[node + 1];
    float a0=0,a1=0,a2=0,a3=0,a4=0,a5=0,a6=0,a7=0;
    int p = p0;
    for (; p + 2 <= p1; p += 2) {
        const int s0 = cs[p], s1 = cs[p + 1];
        const float e0 = ca[p], e1 = ca[p + 1];
        const uint4 G0 = *(const uint4*)(g + (long)s0 * HD + c0);
        const uint4 G1 = *(const uint4*)(g + (long)s1 * HD + c0);
        a0 += fmaxf(fmaf(e0, wla.x, bflo(G0.x)), 0.f) + fmaxf(fmaf(e1, wla.x, bflo(G1.x)), 0.f);
        a1 += fmaxf(fmaf(e0, wla.y, bfhi(G0.x)), 0.f) + fmaxf(fmaf(e1, wla.y, bfhi(G1.x)), 0.f);
        a2 += fmaxf(fmaf(e0, wla.z, bflo(G0.y)), 0.f) + fmaxf(fmaf(e1, wla.z, bflo(G1.y)), 0.f);
        a3 += fmaxf(fmaf(e0, wla.w, bfhi(G0.y)), 0.f) + fmaxf(fmaf(e1, wla.w, bfhi(G1.y)), 0.f);
        a4 += fmaxf(fmaf(e0, wlb.x, bflo(G0.z)), 0.f) + fmaxf(fmaf(e1, wlb.x, bflo(G1.z)), 0.f);
        a5 += fmaxf(fmaf(e0, wlb.y, bfhi(G0.z)), 0.f) + fmaxf(fmaf(e1, wlb.y, bfhi(G1.z)), 0.f);
        a6 += fmaxf(fmaf(e0, wlb.z, bflo(G0.w)), 0.f) + fmaxf(fmaf(e1, wlb.z, bflo(G1.w)), 0.f);
        a7 += fmaxf(fmaf(e0, wlb.w, bfhi(G0.w)), 0.f) + fmaxf(fmaf(e1, wlb.w, bfhi(G1.w)), 0.f);
    }
    if (p < p1) {
        const int s0 = cs[p];
        const float e0 = ca[p];
        const uint4 G0 = *(const uint4*)(g + (long)s0 * HD + c0);
        a0 += fmaxf(fmaf(e0, wla.x, bflo(G0.x)), 0.f);
        a1 += fmaxf(fmaf(e0, wla.y, bfhi(G0.x)), 0.f);
        a2 += fmaxf(fmaf(e0, wla.z, bflo(G0.y)), 0.f);
        a3 += fmaxf(fmaf(e0, wla.w, bfhi(G0.y)), 0.f);
        a4 += fmaxf(fmaf(e0, wlb.x, bflo(G0.z)), 0.f);
        a5 += fmaxf(fmaf(e0, wlb.y, bfhi(G0.z)), 0.f);
        a6 += fmaxf(fmaf(e0, wlb.z, bflo(G0.w)), 0.f);
        a7 += fmaxf(fmaf(e0, wlb.w, bfhi(G0.w)), 0.f);
    }
    const float id = inv_deg[node];
    uint4 o;
    o.x = (unsigned)f2bf(a0 * id) | ((unsigned)f2bf(a1 * id) << 16);
    o.y = (unsigned)f2bf(a2 * id) | ((unsigned)f2bf(a3 * id) << 16);
    o.z = (unsigned)f2bf(a4 * id) | ((unsigned)f2bf(a5 * id) << 16);
    o.w = (unsigned)f2bf(a6 * id) | ((unsigned)f2bf(a7 * id) << 16);
    *(uint4*)(agg + (long)node * HD + c0) = o;
}

extern "C" void kernel_launch(void* const* d_in, const int* in_sizes, int n_in,
                              void* d_out, int out_size, void* d_ws, size_t ws_size,
                              hipStream_t stream)
{
    const float* x     = (const float*)d_in[0];
    const float* eattr = (const float*)d_in[1];
    const float* W_lin = (const float*)d_in[2];
    const float* b_lin = (const float*)d_in[3];
    const float* W_msg = (const float*)d_in[4];
    const float* b_msg = (const float*)d_in[5];
    const float* W_l   = (const float*)d_in[6];
    const float* b_l   = (const float*)d_in[7];
    const float* W_r   = (const float*)d_in[8];
    const float* W_dec = (const float*)d_in[9];
    const float* b_dec = (const float*)d_in[10];
    const float* W_fin = (const float*)d_in[11];
    const float* b_fin = (const float*)d_in[12];
    const int*   ei    = (const int*)d_in[13];

    const int N = in_sizes[0] / HD;   // 100000
    const int E = in_sizes[1];        // 600000
    const int* srcv = ei;
    const int* dstv = ei + E;

    char* wsb = (char*)d_ws;
    size_t off = 0;
    auto carve = [&](size_t bytes) -> void* {
        void* p = wsb + off;
        off += (bytes + 255) & ~(size_t)255;
        return p;
    };
    unsigned short* xb = (unsigned short*)carve((size_t)N * HD * 2);
    unsigned short* t1 = (unsigned short*)carve((size_t)N * HD * 2);
    unsigned short* t2 = (unsigned short*)carve((size_t)N * HD * 2);
    unsigned short* t3 = (unsigned short*)carve((size_t)N * HD * 2);
    unsigned short* wt = (unsigned short*)carve((size_t)14 * 16384 * 2);
    int*   csr_src  = (int*)carve((size_t)E * 4);
    float* csr_attr = (float*)carve((size_t)E * 4);
    int*   rowstart = (int*)carve((size_t)(N + 1) * 4);
    int*   deg      = (int*)carve((size_t)N * 4);
    int*   cursor   = (int*)carve((size_t)N * 4);
    float* inv_deg  = (float*)carve((size_t)N * 4);
    const int NCH = (N + 255) / 256;
    int* csum  = (int*)carve((size_t)NCH * 4);
    int* cbase = (int*)carve((size_t)NCH * 4);

    if (off > ws_size) {
        hipMemsetAsync(d_out, 0, (size_t)out_size * 4, stream);
        return;
    }

    hipMemsetAsync(deg, 0, (size_t)N * 4, stream);
    hipMemsetAsync(cursor, 0, (size_t)N * 4, stream);

    // prep
    k_cast_bf16<<<(int)(((long)N * HD / 8 + 255) / 256), 256, 0, stream>>>(x, xb, (long)N * HD / 8);
    k_prep_w<<<dim3(64, 14), 256, 0, stream>>>(W_lin, W_msg, W_l, W_r, W_dec, W_fin, wt);

    // CSR
    k_deg<<<(E + 255) / 256, 256, 0, stream>>>(srcv, dstv, deg, E, N);
    k_invdeg<<<(N + 255) / 256, 256, 0, stream>>>(deg, inv_deg, N);
    k_chunksum<<<NCH, 256, 0, stream>>>(deg, csum, N);
    k_scanmid<<<1, 512, 0, stream>>>(csum, cbase, rowstart, NCH, N);
    k_scan2<<<NCH, 256, 0, stream>>>(deg, cbase, rowstart, N);
    k_fill<<<(E + 255) / 256, 256, 0, stream>>>(srcv, dstv, eattr, rowstart, cursor,
                                                csr_src, csr_attr, E, N);

    auto WT = [&](int m) { return wt + (size_t)m * 16384; };
    const int NB64 = (N + 63) / 64;
    const int GAGG = (N + 15) / 16;

    const unsigned short* xin = xb;
    for (int l = 0; l < 3; ++l) {
        unsigned short* gb = (l == 1) ? t3 : t2;   // xin rotates xb -> t2 -> t3 -> t2
        // g = relu(x @ W_lin + b_lin) @ Wmsg_top + b_msg   (h stays in LDS)
        k_gemm_s<false, true, 128, false><<<NB64, 256, 0, stream>>>(
            xin, WT(l), nullptr, nullptr, WT(3 + l), b_lin + l * HD, b_msg + l * HD, gb, N);
        // agg = inv_deg * sum relu(g[src] + attr*wlast)  -> t1
        k_agg<<<GAGG, 256, 0, stream>>>(
            gb, csr_src, csr_attr, rowstart, inv_deg,
            W_msg + (size_t)l * (HD + 1) * HD + (size_t)HD * HD, t1, N);
        // x' = relu(agg @ W_l + x @ W_r + b_l) -> gb (g dead; gb != xin)
        k_gemm_s<true, false, 128, false><<<NB64, 256, 0, stream>>>(
            t1, WT(6 + l), xin, WT(9 + l), nullptr, b_l + l * HD, nullptr, gb, N);
        xin = gb;
    }
    // logits = relu(x @ W_dec + b_dec) @ W_fin + b_fin -> d_out (f32)
    k_gemm_s<false, true, 64, true><<<NB64, 256, 0, stream>>>(
        xin, WT(12), nullptr, nullptr, WT(13), b_dec, b_fin, (float*)d_out, N);
}

// Round 5
// 357.696 us; speedup vs baseline: 2.5721x; 1.0342x over previous
//
#include <hip/hip_runtime.h>

using short8 = __attribute__((ext_vector_type(8))) short;
using f32x4  = __attribute__((ext_vector_type(4))) float;

constexpr int HD = 128;

__device__ __forceinline__ unsigned short f2bf(float f) {
    unsigned u = __builtin_bit_cast(unsigned, f);
    u += 0x7fffu + ((u >> 16) & 1u);          // round-to-nearest-even
    return (unsigned short)(u >> 16);
}
__device__ __forceinline__ float bflo(unsigned u) { return __builtin_bit_cast(float, u << 16); }
__device__ __forceinline__ float bfhi(unsigned u) { return __builtin_bit_cast(float, u & 0xffff0000u); }

__device__ __forceinline__ short8 ldg8(const unsigned short* p) {
    return *reinterpret_cast<const short8*>(p);   // 16B contiguous, aligned
}

// ---------------------------------------------------------------------------
// Staged GEMM. Block = 64 rows x 128 cols, 4 waves (wave w -> cols w*32..+31).
// A-tiles stream global->LDS via async global_load_lds (16B/lane, contiguous
// 1KB per wave-instruction). Source addresses are pre-swizzled (chunk ^= row&7,
// m173 pattern) so LDS remains linear for the DMA but ds_read_b128 fragment
// reads spread across 8 bank slots. Weights are loaded to registers from L2.
//   DUAL : Out = relu(A1@Wt1 + A2@Wt2 + b1)
//   CHAIN: Out = (relu(A1@Wt1 + b1)) @ Wtc + b2   (h kept in swizzled LDS)
// ---------------------------------------------------------------------------
template<bool DUAL, bool CHAIN, int NC2, bool F32OUT>
__global__ __launch_bounds__(256)
void k_gemm_s(const unsigned short* __restrict__ A1, const unsigned short* __restrict__ Wt1,
              const unsigned short* __restrict__ A2, const unsigned short* __restrict__ Wt2,
              const unsigned short* __restrict__ Wtc, const float* __restrict__ b1,
              const float* __restrict__ b2, void* __restrict__ Out, int nrows)
{
    __shared__ __align__(16) unsigned short As1[64 * HD];
    __shared__ __align__(16) unsigned short As2[DUAL ? 64 * HD : 8];
    __shared__ __align__(16) unsigned short Hs [CHAIN ? 64 * HD : 8];

    const int tid  = threadIdx.x;
    const int lane = tid & 63, wave = tid >> 6;
    const int lr = lane & 15, lg = lane >> 4;
    const int row0 = blockIdx.x * 64;

    // ---- issue async DMA staging of A tile(s) ----
#pragma unroll
    for (int it = 0; it < 4; ++it) {
        const int q   = wave * 4 + it;          // 1KB chunk id (wave-uniform)
        const int c   = q * 64 + lane;          // 16B chunk id 0..1023
        const int row = c >> 4, cw = c & 15;    // within-tile row, chunk-in-row
        int grow = row0 + row; grow = grow < nrows ? grow : nrows - 1;
        const int gco = (cw ^ (row & 7)) << 3;  // swizzled source element offset
        __builtin_amdgcn_global_load_lds((const unsigned int*)(A1 + (long)grow * HD + gco),
                                         (unsigned int*)&As1[q * 512], 16, 0, 0);
        if constexpr (DUAL)
            __builtin_amdgcn_global_load_lds((const unsigned int*)(A2 + (long)grow * HD + gco),
                                             (unsigned int*)&As2[q * 512], 16, 0, 0);
    }

    // ---- weight fragments (L2-hot), overlap with DMA ----
    const int cb1 = wave * 32;
    short8 bf1[2][4];
#pragma unroll
    for (int ct = 0; ct < 2; ++ct) {
        const unsigned short* bp = Wt1 + (long)(cb1 + ct * 16 + lr) * HD + lg * 8;
#pragma unroll
        for (int kt = 0; kt < 4; ++kt) bf1[ct][kt] = ldg8(bp + kt * 32);
    }
    short8 bf2[DUAL ? 2 : 1][4];
    if constexpr (DUAL) {
#pragma unroll
        for (int ct = 0; ct < 2; ++ct) {
            const unsigned short* bp = Wt2 + (long)(cb1 + ct * 16 + lr) * HD + lg * 8;
#pragma unroll
            for (int kt = 0; kt < 4; ++kt) bf2[ct][kt] = ldg8(bp + kt * 32);
        }
    }
    constexpr int CT2 = CHAIN ? (NC2 / 64) : 1;
    const int cb2 = wave * (NC2 / 4);
    short8 bfc[CT2][4];
    if constexpr (CHAIN) {
#pragma unroll
        for (int ct = 0; ct < CT2; ++ct) {
            const unsigned short* bp = Wtc + (long)(cb2 + ct * 16 + lr) * HD + lg * 8;
#pragma unroll
            for (int kt = 0; kt < 4; ++kt) bfc[ct][kt] = ldg8(bp + kt * 32);
        }
    }

    __syncthreads();   // compiler drains vmcnt (DMA + weight loads) before barrier

    // ---- phase 1 MFMA: acc = A1@Wt1 [+ A2@Wt2] ----
    f32x4 acc[4][2] = {};
#pragma unroll
    for (int kt = 0; kt < 4; ++kt) {
        short8 af[4];
#pragma unroll
        for (int rt = 0; rt < 4; ++rt)
            af[rt] = *reinterpret_cast<const short8*>(
                &As1[(rt * 16 + lr) * HD + (((kt * 4 + lg) ^ (lr & 7)) << 3)]);
#pragma unroll
        for (int rt = 0; rt < 4; ++rt)
#pragma unroll
            for (int ct = 0; ct < 2; ++ct)
                acc[rt][ct] = __builtin_amdgcn_mfma_f32_16x16x32_bf16(af[rt], bf1[ct][kt], acc[rt][ct], 0, 0, 0);
        if constexpr (DUAL) {
            short8 af2[4];
#pragma unroll
            for (int rt = 0; rt < 4; ++rt)
                af2[rt] = *reinterpret_cast<const short8*>(
                    &As2[(rt * 16 + lr) * HD + (((kt * 4 + lg) ^ (lr & 7)) << 3)]);
#pragma unroll
            for (int rt = 0; rt < 4; ++rt)
#pragma unroll
                for (int ct = 0; ct < 2; ++ct)
                    acc[rt][ct] = __builtin_amdgcn_mfma_f32_16x16x32_bf16(af2[rt], bf2[ct][kt], acc[rt][ct], 0, 0, 0);
        }
    }

    const float bv1[2] = { b1[cb1 + lr], b1[cb1 + 16 + lr] };

    if constexpr (!CHAIN) {
        // relu + store bf16
        unsigned short* C = (unsigned short*)Out;
#pragma unroll
        for (int rt = 0; rt < 4; ++rt)
#pragma unroll
            for (int ct = 0; ct < 2; ++ct) {
                const int cc = cb1 + ct * 16 + lr;
#pragma unroll
                for (int i = 0; i < 4; ++i) {
                    const int r = row0 + rt * 16 + lg * 4 + i;
                    if (r < nrows) C[(long)r * HD + cc] = f2bf(fmaxf(acc[rt][ct][i] + bv1[ct], 0.f));
                }
            }
    } else {
        // h = relu(acc + b1) -> Hs (swizzled layout, same read path as As)
#pragma unroll
        for (int rt = 0; rt < 4; ++rt)
#pragma unroll
            for (int ct = 0; ct < 2; ++ct) {
                const int cc = cb1 + ct * 16 + lr;
#pragma unroll
                for (int i = 0; i < 4; ++i) {
                    const int row = rt * 16 + lg * 4 + i;
                    const float v = fmaxf(acc[rt][ct][i] + bv1[ct], 0.f);
                    Hs[row * HD + ((((cc >> 3) ^ (row & 7)) << 3) | (cc & 7))] = f2bf(v);
                }
            }
        __syncthreads();

        // ---- phase 2: Out = h @ Wtc + b2 ----
        f32x4 acc2[4][CT2] = {};
#pragma unroll
        for (int kt = 0; kt < 4; ++kt) {
            short8 ah[4];
#pragma unroll
            for (int rt = 0; rt < 4; ++rt)
                ah[rt] = *reinterpret_cast<const short8*>(
                    &Hs[(rt * 16 + lr) * HD + (((kt * 4 + lg) ^ (lr & 7)) << 3)]);
#pragma unroll
            for (int rt = 0; rt < 4; ++rt)
#pragma unroll
                for (int ct = 0; ct < CT2; ++ct)
                    acc2[rt][ct] = __builtin_amdgcn_mfma_f32_16x16x32_bf16(ah[rt], bfc[ct][kt], acc2[rt][ct], 0, 0, 0);
        }
        float bv2[CT2];
#pragma unroll
        for (int ct = 0; ct < CT2; ++ct) bv2[ct] = b2[cb2 + ct * 16 + lr];
#pragma unroll
        for (int rt = 0; rt < 4; ++rt)
#pragma unroll
            for (int ct = 0; ct < CT2; ++ct) {
                const int cc = cb2 + ct * 16 + lr;
#pragma unroll
                for (int i = 0; i < 4; ++i) {
                    const int r = row0 + rt * 16 + lg * 4 + i;
                    if (r < nrows) {
                        const float v = acc2[rt][ct][i] + bv2[ct];
                        if constexpr (F32OUT) ((float*)Out)[(long)r * NC2 + cc] = v;
                        else ((unsigned short*)Out)[(long)r * NC2 + cc] = f2bf(v);
                    }
                }
            }
    }
}

// ---- prep: cast x fp32 -> bf16 (vectorized) ----
__global__ void k_cast_bf16(const float* __restrict__ in, unsigned short* __restrict__ out, long n8) {
    long i = (long)blockIdx.x * 256 + threadIdx.x;
    if (i >= n8) return;
    const float4 v0 = *((const float4*)in + i * 2);
    const float4 v1 = *((const float4*)in + i * 2 + 1);
    unsigned o[4];
    o[0] = (unsigned)f2bf(v0.x) | ((unsigned)f2bf(v0.y) << 16);
    o[1] = (unsigned)f2bf(v0.z) | ((unsigned)f2bf(v0.w) << 16);
    o[2] = (unsigned)f2bf(v1.x) | ((unsigned)f2bf(v1.y) << 16);
    o[3] = (unsigned)f2bf(v1.z) | ((unsigned)f2bf(v1.w) << 16);
    *(uint4*)(out + i * 8) = *(uint4*)o;
}

// ---- prep: cast + transpose weights into wt[m][c][k] bf16 ----
// m: 0-2 W_lin, 3-5 W_msg(top 128), 6-8 W_l, 9-11 W_r, 12 W_dec, 13 W_fin(C=64)
__global__ void k_prep_w(const float* __restrict__ Wlin, const float* __restrict__ Wmsg,
                         const float* __restrict__ Wl,   const float* __restrict__ Wr,
                         const float* __restrict__ Wdec, const float* __restrict__ Wfin,
                         unsigned short* __restrict__ wt)
{
    const int m = blockIdx.y;
    const float* src; int C = 128;
    if      (m < 3)  src = Wlin + m * 16384;
    else if (m < 6)  src = Wmsg + (m - 3) * (129 * 128);
    else if (m < 9)  src = Wl   + (m - 6) * 16384;
    else if (m < 12) src = Wr   + (m - 9) * 16384;
    else if (m == 12) src = Wdec;
    else { src = Wfin; C = 64; }
    const int elems = C * 128;
    int e = blockIdx.x * 256 + threadIdx.x;
    if (e >= elems) return;
    int c = e >> 7, k = e & 127;
    wt[m * 16384 + e] = f2bf(src[k * C + c]);
}

// ---- CSR build ----
__global__ void k_deg(const int* __restrict__ src, const int* __restrict__ dst,
                      int* __restrict__ deg, int nE, int n) {
    int e = blockIdx.x * 256 + threadIdx.x;
    if (e >= nE) return;
    unsigned d = (unsigned)dst[e], s = (unsigned)src[e];
    if (d < (unsigned)n && s < (unsigned)n) atomicAdd(&deg[d], 1);
}

__global__ void k_chunksum(const int* __restrict__ deg, int* __restrict__ csum, int n) {
    __shared__ int s[256];
    int t = threadIdx.x, i = blockIdx.x * 256 + t;
    s[t] = (i < n) ? deg[i] : 0;
    __syncthreads();
    for (int o = 128; o > 0; o >>= 1) { if (t < o) s[t] += s[t + o]; __syncthreads(); }
    if (t == 0) csum[blockIdx.x] = s[0];
}

__global__ void k_scanmid(const int* __restrict__ csum, int* __restrict__ cbase,
                          int* __restrict__ rowstart, int nch, int n) {
    __shared__ int s[512];
    int t = threadIdx.x;
    int v = (t < nch) ? csum[t] : 0;
    s[t] = v; __syncthreads();
    for (int off = 1; off < 512; off <<= 1) {
        int tmp = (t >= off) ? s[t - off] : 0;
        __syncthreads();
        s[t] += tmp;
        __syncthreads();
    }
    if (t < nch) cbase[t] = s[t] - v;
    if (t == nch - 1) rowstart[n] = s[t];
}

// scan within chunk + fused inv_deg (deg value is already in hand here)
__global__ void k_scan2(const int* __restrict__ deg, const int* __restrict__ cbase,
                        int* __restrict__ rowstart, float* __restrict__ inv_deg, int n) {
    __shared__ int s[256];
    int t = threadIdx.x, i = blockIdx.x * 256 + t;
    int v = (i < n) ? deg[i] : 0;
    s[t] = v; __syncthreads();
    for (int off = 1; off < 256; off <<= 1) {
        int tmp = (t >= off) ? s[t - off] : 0;
        __syncthreads();
        s[t] += tmp;
        __syncthreads();
    }
    if (i < n) {
        rowstart[i] = cbase[blockIdx.x] + s[t] - v;
        inv_deg[i] = 1.0f / fmaxf((float)v, 1.0f);
    }
}

// one packed 8B record per edge: {src, attr_bits}. deg doubles as downward
// cursor (atomicSub) -- it is dead after k_scan2.
__global__ void k_fill(const int* __restrict__ src, const int* __restrict__ dst,
                       const float* __restrict__ eattr, const int* __restrict__ rowstart,
                       int* __restrict__ degcur, uint2* __restrict__ csr_rec, int nE, int n) {
    int e = blockIdx.x * 256 + threadIdx.x;
    if (e >= nE) return;
    unsigned d = (unsigned)dst[e], s = (unsigned)src[e];
    if (d < (unsigned)n && s < (unsigned)n) {
        int p = rowstart[d] + atomicSub(&degcur[d], 1) - 1;
        uint2 rec;
        rec.x = s;
        rec.y = __builtin_bit_cast(unsigned, eattr[e]);
        csr_rec[p] = rec;
    }
}

// agg[i] = bf16( inv_deg[i] * sum_p relu(g[src_p] + attr_p * wlast) )
// 16 lanes/node, 16B/lane, 2-edge unroll, packed uint2 records.
__global__ __launch_bounds__(256)
void k_agg(const unsigned short* __restrict__ g, const uint2* __restrict__ rec,
           const int* __restrict__ rs, const float* __restrict__ inv_deg,
           const float* __restrict__ wlast, unsigned short* __restrict__ agg, int n) {
    const int lane = threadIdx.x & 15;
    const int node = blockIdx.x * 16 + (threadIdx.x >> 4);
    if (node >= n) return;
    const int c0 = lane * 8;
    const float4 wla = *(const float4*)(wlast + c0);
    const float4 wlb = *(const float4*)(wlast + c0 + 4);
    const int p0 = rs[node], p1 = rs[node + 1];
    float a0=0,a1=0,a2=0,a3=0,a4=0,a5=0,a6=0,a7=0;
    int p = p0;
    for (; p + 2 <= p1; p += 2) {
        const uint2 r0 = rec[p], r1 = rec[p + 1];
        const float e0 = __builtin_bit_cast(float, r0.y);
        const float e1 = __builtin_bit_cast(float, r1.y);
        const uint4 G0 = *(const uint4*)(g + (long)r0.x * HD + c0);
        const uint4 G1 = *(const uint4*)(g + (long)r1.x * HD + c0);
        a0 += fmaxf(fmaf(e0, wla.x, bflo(G0.x)), 0.f) + fmaxf(fmaf(e1, wla.x, bflo(G1.x)), 0.f);
        a1 += fmaxf(fmaf(e0, wla.y, bfhi(G0.x)), 0.f) + fmaxf(fmaf(e1, wla.y, bfhi(G1.x)), 0.f);
        a2 += fmaxf(fmaf(e0, wla.z, bflo(G0.y)), 0.f) + fmaxf(fmaf(e1, wla.z, bflo(G1.y)), 0.f);
        a3 += fmaxf(fmaf(e0, wla.w, bfhi(G0.y)), 0.f) + fmaxf(fmaf(e1, wla.w, bfhi(G1.y)), 0.f);
        a4 += fmaxf(fmaf(e0, wlb.x, bflo(G0.z)), 0.f) + fmaxf(fmaf(e1, wlb.x, bflo(G1.z)), 0.f);
        a5 += fmaxf(fmaf(e0, wlb.y, bfhi(G0.z)), 0.f) + fmaxf(fmaf(e1, wlb.y, bfhi(G1.z)), 0.f);
        a6 += fmaxf(fmaf(e0, wlb.z, bflo(G0.w)), 0.f) + fmaxf(fmaf(e1, wlb.z, bflo(G1.w)), 0.f);
        a7 += fmaxf(fmaf(e0, wlb.w, bfhi(G0.w)), 0.f) + fmaxf(fmaf(e1, wlb.w, bfhi(G1.w)), 0.f);
    }
    if (p < p1) {
        const uint2 r0 = rec[p];
        const float e0 = __builtin_bit_cast(float, r0.y);
        const uint4 G0 = *(const uint4*)(g + (long)r0.x * HD + c0);
        a0 += fmaxf(fmaf(e0, wla.x, bflo(G0.x)), 0.f);
        a1 += fmaxf(fmaf(e0, wla.y, bfhi(G0.x)), 0.f);
        a2 += fmaxf(fmaf(e0, wla.z, bflo(G0.y)), 0.f);
        a3 += fmaxf(fmaf(e0, wla.w, bfhi(G0.y)), 0.f);
        a4 += fmaxf(fmaf(e0, wlb.x, bflo(G0.z)), 0.f);
        a5 += fmaxf(fmaf(e0, wlb.y, bfhi(G0.z)), 0.f);
        a6 += fmaxf(fmaf(e0, wlb.z, bflo(G0.w)), 0.f);
        a7 += fmaxf(fmaf(e0, wlb.w, bfhi(G0.w)), 0.f);
    }
    const float id = inv_deg[node];
    uint4 o;
    o.x = (unsigned)f2bf(a0 * id) | ((unsigned)f2bf(a1 * id) << 16);
    o.y = (unsigned)f2bf(a2 * id) | ((unsigned)f2bf(a3 * id) << 16);
    o.z = (unsigned)f2bf(a4 * id) | ((unsigned)f2bf(a5 * id) << 16);
    o.w = (unsigned)f2bf(a6 * id) | ((unsigned)f2bf(a7 * id) << 16);
    *(uint4*)(agg + (long)node * HD + c0) = o;
}

extern "C" void kernel_launch(void* const* d_in, const int* in_sizes, int n_in,
                              void* d_out, int out_size, void* d_ws, size_t ws_size,
                              hipStream_t stream)
{
    const float* x     = (const float*)d_in[0];
    const float* eattr = (const float*)d_in[1];
    const float* W_lin = (const float*)d_in[2];
    const float* b_lin = (const float*)d_in[3];
    const float* W_msg = (const float*)d_in[4];
    const float* b_msg = (const float*)d_in[5];
    const float* W_l   = (const float*)d_in[6];
    const float* b_l   = (const float*)d_in[7];
    const float* W_r   = (const float*)d_in[8];
    const float* W_dec = (const float*)d_in[9];
    const float* b_dec = (const float*)d_in[10];
    const float* W_fin = (const float*)d_in[11];
    const float* b_fin = (const float*)d_in[12];
    const int*   ei    = (const int*)d_in[13];

    const int N = in_sizes[0] / HD;   // 100000
    const int E = in_sizes[1];        // 600000
    const int* srcv = ei;
    const int* dstv = ei + E;

    char* wsb = (char*)d_ws;
    size_t off = 0;
    auto carve = [&](size_t bytes) -> void* {
        void* p = wsb + off;
        off += (bytes + 255) & ~(size_t)255;
        return p;
    };
    unsigned short* xb = (unsigned short*)carve((size_t)N * HD * 2);
    unsigned short* t1 = (unsigned short*)carve((size_t)N * HD * 2);
    unsigned short* t2 = (unsigned short*)carve((size_t)N * HD * 2);
    unsigned short* t3 = (unsigned short*)carve((size_t)N * HD * 2);
    unsigned short* wt = (unsigned short*)carve((size_t)14 * 16384 * 2);
    uint2* csr_rec  = (uint2*)carve((size_t)E * 8);
    int*   rowstart = (int*)carve((size_t)(N + 1) * 4);
    int*   deg      = (int*)carve((size_t)N * 4);
    float* inv_deg  = (float*)carve((size_t)N * 4);
    const int NCH = (N + 255) / 256;
    int* csum  = (int*)carve((size_t)NCH * 4);
    int* cbase = (int*)carve((size_t)NCH * 4);

    if (off > ws_size) {
        hipMemsetAsync(d_out, 0, (size_t)out_size * 4, stream);
        return;
    }

    hipMemsetAsync(deg, 0, (size_t)N * 4, stream);

    // prep
    k_cast_bf16<<<(int)(((long)N * HD / 8 + 255) / 256), 256, 0, stream>>>(x, xb, (long)N * HD / 8);
    k_prep_w<<<dim3(64, 14), 256, 0, stream>>>(W_lin, W_msg, W_l, W_r, W_dec, W_fin, wt);

    // CSR
    k_deg<<<(E + 255) / 256, 256, 0, stream>>>(srcv, dstv, deg, E, N);
    k_chunksum<<<NCH, 256, 0, stream>>>(deg, csum, N);
    k_scanmid<<<1, 512, 0, stream>>>(csum, cbase, rowstart, NCH, N);
    k_scan2<<<NCH, 256, 0, stream>>>(deg, cbase, rowstart, inv_deg, N);
    k_fill<<<(E + 255) / 256, 256, 0, stream>>>(srcv, dstv, eattr, rowstart, deg,
                                                csr_rec, E, N);

    auto WT = [&](int m) { return wt + (size_t)m * 16384; };
    const int NB64 = (N + 63) / 64;
    const int GAGG = (N + 15) / 16;

    const unsigned short* xin = xb;
    for (int l = 0; l < 3; ++l) {
        unsigned short* gb = (l == 1) ? t3 : t2;   // xin rotates xb -> t2 -> t3 -> t2
        // g = relu(x @ W_lin + b_lin) @ Wmsg_top + b_msg   (h stays in LDS)
        k_gemm_s<false, true, 128, false><<<NB64, 256, 0, stream>>>(
            xin, WT(l), nullptr, nullptr, WT(3 + l), b_lin + l * HD, b_msg + l * HD, gb, N);
        // agg = inv_deg * sum relu(g[src] + attr*wlast)  -> t1
        k_agg<<<GAGG, 256, 0, stream>>>(
            gb, csr_rec, rowstart, inv_deg,
            W_msg + (size_t)l * (HD + 1) * HD + (size_t)HD * HD, t1, N);
        // x' = relu(agg @ W_l + x @ W_r + b_l) -> gb (g dead; gb != xin)
        k_gemm_s<true, false, 128, false><<<NB64, 256, 0, stream>>>(
            t1, WT(6 + l), xin, WT(9 + l), nullptr, b_l + l * HD, nullptr, gb, N);
        xin = gb;
    }
    // logits = relu(x @ W_dec + b_dec) @ W_fin + b_fin -> d_out (f32)
    k_gemm_s<false, true, 64, true><<<NB64, 256, 0, stream>>>(
        xin, WT(12), nullptr, nullptr, WT(13), b_dec, b_fin, (float*)d_out, N);
}

// Round 6
// 355.077 us; speedup vs baseline: 2.5911x; 1.0074x over previous
//
#include <hip/hip_runtime.h>

using short8 = __attribute__((ext_vector_type(8))) short;
using f32x4  = __attribute__((ext_vector_type(4))) float;

constexpr int HD = 128;

__device__ __forceinline__ unsigned short f2bf(float f) {
    unsigned u = __builtin_bit_cast(unsigned, f);
    u += 0x7fffu + ((u >> 16) & 1u);          // round-to-nearest-even
    return (unsigned short)(u >> 16);
}
__device__ __forceinline__ float bflo(unsigned u) { return __builtin_bit_cast(float, u << 16); }
__device__ __forceinline__ float bfhi(unsigned u) { return __builtin_bit_cast(float, u & 0xffff0000u); }

__device__ __forceinline__ short8 ldg8(const unsigned short* p) {
    return *reinterpret_cast<const short8*>(p);   // 16B contiguous, aligned
}

// ---------------------------------------------------------------------------
// Staged GEMM. Block = 64 rows x 128 cols, 4 waves (wave w -> cols w*32..+31).
// A-tiles stream global->LDS via async global_load_lds (16B/lane, contiguous
// 1KB per wave-instruction). Source addresses are pre-swizzled (chunk ^= row&7,
// m173 pattern) so LDS remains linear for the DMA but ds_read_b128 fragment
// reads spread across 8 bank slots. Weights are loaded to registers from L2.
//   DUAL : Out = relu(A1@Wt1 + A2@Wt2 + b1)
//   CHAIN: Out = (relu(A1@Wt1 + b1)) @ Wtc + b2   (h kept in swizzled LDS)
// ---------------------------------------------------------------------------
template<bool DUAL, bool CHAIN, int NC2, bool F32OUT>
__global__ __launch_bounds__(256)
void k_gemm_s(const unsigned short* __restrict__ A1, const unsigned short* __restrict__ Wt1,
              const unsigned short* __restrict__ A2, const unsigned short* __restrict__ Wt2,
              const unsigned short* __restrict__ Wtc, const float* __restrict__ b1,
              const float* __restrict__ b2, void* __restrict__ Out, int nrows)
{
    __shared__ __align__(16) unsigned short As1[64 * HD];
    __shared__ __align__(16) unsigned short As2[DUAL ? 64 * HD : 8];
    __shared__ __align__(16) unsigned short Hs [CHAIN ? 64 * HD : 8];

    const int tid  = threadIdx.x;
    const int lane = tid & 63, wave = tid >> 6;
    const int lr = lane & 15, lg = lane >> 4;
    const int row0 = blockIdx.x * 64;

    // ---- issue async DMA staging of A tile(s) ----
#pragma unroll
    for (int it = 0; it < 4; ++it) {
        const int q   = wave * 4 + it;          // 1KB chunk id (wave-uniform)
        const int c   = q * 64 + lane;          // 16B chunk id 0..1023
        const int row = c >> 4, cw = c & 15;    // within-tile row, chunk-in-row
        int grow = row0 + row; grow = grow < nrows ? grow : nrows - 1;
        const int gco = (cw ^ (row & 7)) << 3;  // swizzled source element offset
        __builtin_amdgcn_global_load_lds((const unsigned int*)(A1 + (long)grow * HD + gco),
                                         (unsigned int*)&As1[q * 512], 16, 0, 0);
        if constexpr (DUAL)
            __builtin_amdgcn_global_load_lds((const unsigned int*)(A2 + (long)grow * HD + gco),
                                             (unsigned int*)&As2[q * 512], 16, 0, 0);
    }

    // ---- weight fragments (L2-hot), overlap with DMA ----
    const int cb1 = wave * 32;
    short8 bf1[2][4];
#pragma unroll
    for (int ct = 0; ct < 2; ++ct) {
        const unsigned short* bp = Wt1 + (long)(cb1 + ct * 16 + lr) * HD + lg * 8;
#pragma unroll
        for (int kt = 0; kt < 4; ++kt) bf1[ct][kt] = ldg8(bp + kt * 32);
    }
    short8 bf2[DUAL ? 2 : 1][4];
    if constexpr (DUAL) {
#pragma unroll
        for (int ct = 0; ct < 2; ++ct) {
            const unsigned short* bp = Wt2 + (long)(cb1 + ct * 16 + lr) * HD + lg * 8;
#pragma unroll
            for (int kt = 0; kt < 4; ++kt) bf2[ct][kt] = ldg8(bp + kt * 32);
        }
    }
    constexpr int CT2 = CHAIN ? (NC2 / 64) : 1;
    const int cb2 = wave * (NC2 / 4);
    short8 bfc[CT2][4];
    if constexpr (CHAIN) {
#pragma unroll
        for (int ct = 0; ct < CT2; ++ct) {
            const unsigned short* bp = Wtc + (long)(cb2 + ct * 16 + lr) * HD + lg * 8;
#pragma unroll
            for (int kt = 0; kt < 4; ++kt) bfc[ct][kt] = ldg8(bp + kt * 32);
        }
    }

    __syncthreads();   // compiler drains vmcnt (DMA + weight loads) before barrier

    // ---- phase 1 MFMA: acc = A1@Wt1 [+ A2@Wt2] ----
    f32x4 acc[4][2] = {};
#pragma unroll
    for (int kt = 0; kt < 4; ++kt) {
        short8 af[4];
#pragma unroll
        for (int rt = 0; rt < 4; ++rt)
            af[rt] = *reinterpret_cast<const short8*>(
                &As1[(rt * 16 + lr) * HD + (((kt * 4 + lg) ^ (lr & 7)) << 3)]);
#pragma unroll
        for (int rt = 0; rt < 4; ++rt)
#pragma unroll
            for (int ct = 0; ct < 2; ++ct)
                acc[rt][ct] = __builtin_amdgcn_mfma_f32_16x16x32_bf16(af[rt], bf1[ct][kt], acc[rt][ct], 0, 0, 0);
        if constexpr (DUAL) {
            short8 af2[4];
#pragma unroll
            for (int rt = 0; rt < 4; ++rt)
                af2[rt] = *reinterpret_cast<const short8*>(
                    &As2[(rt * 16 + lr) * HD + (((kt * 4 + lg) ^ (lr & 7)) << 3)]);
#pragma unroll
            for (int rt = 0; rt < 4; ++rt)
#pragma unroll
                for (int ct = 0; ct < 2; ++ct)
                    acc[rt][ct] = __builtin_amdgcn_mfma_f32_16x16x32_bf16(af2[rt], bf2[ct][kt], acc[rt][ct], 0, 0, 0);
        }
    }

    const float bv1[2] = { b1[cb1 + lr], b1[cb1 + 16 + lr] };

    if constexpr (!CHAIN) {
        // relu + store bf16
        unsigned short* C = (unsigned short*)Out;
#pragma unroll
        for (int rt = 0; rt < 4; ++rt)
#pragma unroll
            for (int ct = 0; ct < 2; ++ct) {
                const int cc = cb1 + ct * 16 + lr;
#pragma unroll
                for (int i = 0; i < 4; ++i) {
                    const int r = row0 + rt * 16 + lg * 4 + i;
                    if (r < nrows) C[(long)r * HD + cc] = f2bf(fmaxf(acc[rt][ct][i] + bv1[ct], 0.f));
                }
            }
    } else {
        // h = relu(acc + b1) -> Hs (swizzled layout, same read path as As)
#pragma unroll
        for (int rt = 0; rt < 4; ++rt)
#pragma unroll
            for (int ct = 0; ct < 2; ++ct) {
                const int cc = cb1 + ct * 16 + lr;
#pragma unroll
                for (int i = 0; i < 4; ++i) {
                    const int row = rt * 16 + lg * 4 + i;
                    const float v = fmaxf(acc[rt][ct][i] + bv1[ct], 0.f);
                    Hs[row * HD + ((((cc >> 3) ^ (row & 7)) << 3) | (cc & 7))] = f2bf(v);
                }
            }
        __syncthreads();

        // ---- phase 2: Out = h @ Wtc + b2 ----
        f32x4 acc2[4][CT2] = {};
#pragma unroll
        for (int kt = 0; kt < 4; ++kt) {
            short8 ah[4];
#pragma unroll
            for (int rt = 0; rt < 4; ++rt)
                ah[rt] = *reinterpret_cast<const short8*>(
                    &Hs[(rt * 16 + lr) * HD + (((kt * 4 + lg) ^ (lr & 7)) << 3)]);
#pragma unroll
            for (int rt = 0; rt < 4; ++rt)
#pragma unroll
                for (int ct = 0; ct < CT2; ++ct)
                    acc2[rt][ct] = __builtin_amdgcn_mfma_f32_16x16x32_bf16(ah[rt], bfc[ct][kt], acc2[rt][ct], 0, 0, 0);
        }
        float bv2[CT2];
#pragma unroll
        for (int ct = 0; ct < CT2; ++ct) bv2[ct] = b2[cb2 + ct * 16 + lr];
#pragma unroll
        for (int rt = 0; rt < 4; ++rt)
#pragma unroll
            for (int ct = 0; ct < CT2; ++ct) {
                const int cc = cb2 + ct * 16 + lr;
#pragma unroll
                for (int i = 0; i < 4; ++i) {
                    const int r = row0 + rt * 16 + lg * 4 + i;
                    if (r < nrows) {
                        const float v = acc2[rt][ct][i] + bv2[ct];
                        if constexpr (F32OUT) ((float*)Out)[(long)r * NC2 + cc] = v;
                        else ((unsigned short*)Out)[(long)r * NC2 + cc] = f2bf(v);
                    }
                }
            }
    }
}

// ---- prep: cast x fp32 -> bf16 (vectorized) ----
__global__ void k_cast_bf16(const float* __restrict__ in, unsigned short* __restrict__ out, long n8) {
    long i = (long)blockIdx.x * 256 + threadIdx.x;
    if (i >= n8) return;
    const float4 v0 = *((const float4*)in + i * 2);
    const float4 v1 = *((const float4*)in + i * 2 + 1);
    unsigned o[4];
    o[0] = (unsigned)f2bf(v0.x) | ((unsigned)f2bf(v0.y) << 16);
    o[1] = (unsigned)f2bf(v0.z) | ((unsigned)f2bf(v0.w) << 16);
    o[2] = (unsigned)f2bf(v1.x) | ((unsigned)f2bf(v1.y) << 16);
    o[3] = (unsigned)f2bf(v1.z) | ((unsigned)f2bf(v1.w) << 16);
    *(uint4*)(out + i * 8) = *(uint4*)o;
}

// ---- prep: cast + transpose weights into wt[m][c][k] bf16 ----
// m: 0-2 W_lin, 3-5 W_msg(top 128), 6-8 W_l, 9-11 W_r, 12 W_dec, 13 W_fin(C=64)
__global__ void k_prep_w(const float* __restrict__ Wlin, const float* __restrict__ Wmsg,
                         const float* __restrict__ Wl,   const float* __restrict__ Wr,
                         const float* __restrict__ Wdec, const float* __restrict__ Wfin,
                         unsigned short* __restrict__ wt)
{
    const int m = blockIdx.y;
    const float* src; int C = 128;
    if      (m < 3)  src = Wlin + m * 16384;
    else if (m < 6)  src = Wmsg + (m - 3) * (129 * 128);
    else if (m < 9)  src = Wl   + (m - 6) * 16384;
    else if (m < 12) src = Wr   + (m - 9) * 16384;
    else if (m == 12) src = Wdec;
    else { src = Wfin; C = 64; }
    const int elems = C * 128;
    int e = blockIdx.x * 256 + threadIdx.x;
    if (e >= elems) return;
    int c = e >> 7, k = e & 127;
    wt[m * 16384 + e] = f2bf(src[k * C + c]);
}

// ---- CSR build, XCD-affine ----
// Node range is partitioned into 8 chunks; group (blockIdx&7) handles only
// edges whose dst is in its chunk. With round-robin block->XCD dispatch the
// deg/rowstart/rec lines for a chunk are touched by ONE XCD's L2 only (no
// cross-XCD line ping-pong). Correctness does not depend on the mapping.
__global__ void k_deg(const int* __restrict__ dst, int* __restrict__ deg, int nE, int n) {
    const int grp = blockIdx.x & 7;
    const int bin = blockIdx.x >> 3;
    const int nbin = gridDim.x >> 3;
    const int chunk = (n + 7) >> 3;
    const int lo = grp * chunk;
    const int hi = min(n, lo + chunk);
    for (int e = bin * 256 + threadIdx.x; e < nE; e += nbin * 256) {
        const int d = dst[e];
        if (d >= lo && d < hi) atomicAdd(&deg[d], 1);
    }
}

__global__ void k_chunksum(const int* __restrict__ deg, int* __restrict__ csum, int n) {
    __shared__ int s[256];
    int t = threadIdx.x, i = blockIdx.x * 256 + t;
    s[t] = (i < n) ? deg[i] : 0;
    __syncthreads();
    for (int o = 128; o > 0; o >>= 1) { if (t < o) s[t] += s[t + o]; __syncthreads(); }
    if (t == 0) csum[blockIdx.x] = s[0];
}

__global__ void k_scanmid(const int* __restrict__ csum, int* __restrict__ cbase,
                          int* __restrict__ rowstart, int nch, int n) {
    __shared__ int s[512];
    int t = threadIdx.x;
    int v = (t < nch) ? csum[t] : 0;
    s[t] = v; __syncthreads();
    for (int off = 1; off < 512; off <<= 1) {
        int tmp = (t >= off) ? s[t - off] : 0;
        __syncthreads();
        s[t] += tmp;
        __syncthreads();
    }
    if (t < nch) cbase[t] = s[t] - v;
    if (t == nch - 1) rowstart[n] = s[t];
}

// scan within chunk + fused inv_deg (deg value is already in hand here)
__global__ void k_scan2(const int* __restrict__ deg, const int* __restrict__ cbase,
                        int* __restrict__ rowstart, float* __restrict__ inv_deg, int n) {
    __shared__ int s[256];
    int t = threadIdx.x, i = blockIdx.x * 256 + t;
    int v = (i < n) ? deg[i] : 0;
    s[t] = v; __syncthreads();
    for (int off = 1; off < 256; off <<= 1) {
        int tmp = (t >= off) ? s[t - off] : 0;
        __syncthreads();
        s[t] += tmp;
        __syncthreads();
    }
    if (i < n) {
        rowstart[i] = cbase[blockIdx.x] + s[t] - v;
        inv_deg[i] = 1.0f / fmaxf((float)v, 1.0f);
    }
}

// one packed 8B record per edge: {src, attr_bits}. deg doubles as downward
// cursor (atomicSub) -- it is dead after k_scan2. XCD-affine like k_deg.
__global__ void k_fill(const int* __restrict__ src, const int* __restrict__ dst,
                       const float* __restrict__ eattr, const int* __restrict__ rowstart,
                       int* __restrict__ degcur, uint2* __restrict__ csr_rec, int nE, int n) {
    const int grp = blockIdx.x & 7;
    const int bin = blockIdx.x >> 3;
    const int nbin = gridDim.x >> 3;
    const int chunk = (n + 7) >> 3;
    const int lo = grp * chunk;
    const int hi = min(n, lo + chunk);
    for (int e = bin * 256 + threadIdx.x; e < nE; e += nbin * 256) {
        const int d = dst[e];
        if (d >= lo && d < hi) {
            const int p = rowstart[d] + atomicSub(&degcur[d], 1) - 1;
            uint2 rec;
            rec.x = (unsigned)src[e];
            rec.y = __builtin_bit_cast(unsigned, eattr[e]);
            csr_rec[p] = rec;
        }
    }
}

// agg[i] = bf16( inv_deg[i] * sum_p relu(g[src_p] + attr_p * wlast) )
// 16 lanes/node, 16B/lane, 2-edge unroll, packed uint2 records.
__global__ __launch_bounds__(256)
void k_agg(const unsigned short* __restrict__ g, const uint2* __restrict__ rec,
           const int* __restrict__ rs, const float* __restrict__ inv_deg,
           const float* __restrict__ wlast, unsigned short* __restrict__ agg, int n) {
    const int lane = threadIdx.x & 15;
    const int node = blockIdx.x * 16 + (threadIdx.x >> 4);
    if (node >= n) return;
    const int c0 = lane * 8;
    const float4 wla = *(const float4*)(wlast + c0);
    const float4 wlb = *(const float4*)(wlast + c0 + 4);
    const int p0 = rs[node], p1 = rs[node + 1];
    float a0=0,a1=0,a2=0,a3=0,a4=0,a5=0,a6=0,a7=0;
    int p = p0;
    for (; p + 2 <= p1; p += 2) {
        const uint2 r0 = rec[p], r1 = rec[p + 1];
        const float e0 = __builtin_bit_cast(float, r0.y);
        const float e1 = __builtin_bit_cast(float, r1.y);
        const uint4 G0 = *(const uint4*)(g + (long)r0.x * HD + c0);
        const uint4 G1 = *(const uint4*)(g + (long)r1.x * HD + c0);
        a0 += fmaxf(fmaf(e0, wla.x, bflo(G0.x)), 0.f) + fmaxf(fmaf(e1, wla.x, bflo(G1.x)), 0.f);
        a1 += fmaxf(fmaf(e0, wla.y, bfhi(G0.x)), 0.f) + fmaxf(fmaf(e1, wla.y, bfhi(G1.x)), 0.f);
        a2 += fmaxf(fmaf(e0, wla.z, bflo(G0.y)), 0.f) + fmaxf(fmaf(e1, wla.z, bflo(G1.y)), 0.f);
        a3 += fmaxf(fmaf(e0, wla.w, bfhi(G0.y)), 0.f) + fmaxf(fmaf(e1, wla.w, bfhi(G1.y)), 0.f);
        a4 += fmaxf(fmaf(e0, wlb.x, bflo(G0.z)), 0.f) + fmaxf(fmaf(e1, wlb.x, bflo(G1.z)), 0.f);
        a5 += fmaxf(fmaf(e0, wlb.y, bfhi(G0.z)), 0.f) + fmaxf(fmaf(e1, wlb.y, bfhi(G1.z)), 0.f);
        a6 += fmaxf(fmaf(e0, wlb.z, bflo(G0.w)), 0.f) + fmaxf(fmaf(e1, wlb.z, bflo(G1.w)), 0.f);
        a7 += fmaxf(fmaf(e0, wlb.w, bfhi(G0.w)), 0.f) + fmaxf(fmaf(e1, wlb.w, bfhi(G1.w)), 0.f);
    }
    if (p < p1) {
        const uint2 r0 = rec[p];
        const float e0 = __builtin_bit_cast(float, r0.y);
        const uint4 G0 = *(const uint4*)(g + (long)r0.x * HD + c0);
        a0 += fmaxf(fmaf(e0, wla.x, bflo(G0.x)), 0.f);
        a1 += fmaxf(fmaf(e0, wla.y, bfhi(G0.x)), 0.f);
        a2 += fmaxf(fmaf(e0, wla.z, bflo(G0.y)), 0.f);
        a3 += fmaxf(fmaf(e0, wla.w, bfhi(G0.y)), 0.f);
        a4 += fmaxf(fmaf(e0, wlb.x, bflo(G0.z)), 0.f);
        a5 += fmaxf(fmaf(e0, wlb.y, bfhi(G0.z)), 0.f);
        a6 += fmaxf(fmaf(e0, wlb.z, bflo(G0.w)), 0.f);
        a7 += fmaxf(fmaf(e0, wlb.w, bfhi(G0.w)), 0.f);
    }
    const float id = inv_deg[node];
    uint4 o;
    o.x = (unsigned)f2bf(a0 * id) | ((unsigned)f2bf(a1 * id) << 16);
    o.y = (unsigned)f2bf(a2 * id) | ((unsigned)f2bf(a3 * id) << 16);
    o.z = (unsigned)f2bf(a4 * id) | ((unsigned)f2bf(a5 * id) << 16);
    o.w = (unsigned)f2bf(a6 * id) | ((unsigned)f2bf(a7 * id) << 16);
    *(uint4*)(agg + (long)node * HD + c0) = o;
}

extern "C" void kernel_launch(void* const* d_in, const int* in_sizes, int n_in,
                              void* d_out, int out_size, void* d_ws, size_t ws_size,
                              hipStream_t stream)
{
    const float* x     = (const float*)d_in[0];
    const float* eattr = (const float*)d_in[1];
    const float* W_lin = (const float*)d_in[2];
    const float* b_lin = (const float*)d_in[3];
    const float* W_msg = (const float*)d_in[4];
    const float* b_msg = (const float*)d_in[5];
    const float* W_l   = (const float*)d_in[6];
    const float* b_l   = (const float*)d_in[7];
    const float* W_r   = (const float*)d_in[8];
    const float* W_dec = (const float*)d_in[9];
    const float* b_dec = (const float*)d_in[10];
    const float* W_fin = (const float*)d_in[11];
    const float* b_fin = (const float*)d_in[12];
    const int*   ei    = (const int*)d_in[13];

    const int N = in_sizes[0] / HD;   // 100000
    const int E = in_sizes[1];        // 600000
    const int* srcv = ei;
    const int* dstv = ei + E;

    char* wsb = (char*)d_ws;
    size_t off = 0;
    auto carve = [&](size_t bytes) -> void* {
        void* p = wsb + off;
        off += (bytes + 255) & ~(size_t)255;
        return p;
    };
    unsigned short* xb = (unsigned short*)carve((size_t)N * HD * 2);
    unsigned short* t1 = (unsigned short*)carve((size_t)N * HD * 2);
    unsigned short* t2 = (unsigned short*)carve((size_t)N * HD * 2);
    unsigned short* t3 = (unsigned short*)carve((size_t)N * HD * 2);
    unsigned short* wt = (unsigned short*)carve((size_t)14 * 16384 * 2);
    uint2* csr_rec  = (uint2*)carve((size_t)E * 8);
    int*   rowstart = (int*)carve((size_t)(N + 1) * 4);
    int*   deg      = (int*)carve((size_t)N * 4);
    float* inv_deg  = (float*)carve((size_t)N * 4);
    const int NCH = (N + 255) / 256;
    int* csum  = (int*)carve((size_t)NCH * 4);
    int* cbase = (int*)carve((size_t)NCH * 4);

    if (off > ws_size) {
        hipMemsetAsync(d_out, 0, (size_t)out_size * 4, stream);
        return;
    }

    hipMemsetAsync(deg, 0, (size_t)N * 4, stream);

    // prep
    k_cast_bf16<<<(int)(((long)N * HD / 8 + 255) / 256), 256, 0, stream>>>(x, xb, (long)N * HD / 8);
    k_prep_w<<<dim3(64, 14), 256, 0, stream>>>(W_lin, W_msg, W_l, W_r, W_dec, W_fin, wt);

    // CSR (XCD-affine grids: 8 groups x 256 blocks)
    k_deg<<<2048, 256, 0, stream>>>(dstv, deg, E, N);
    k_chunksum<<<NCH, 256, 0, stream>>>(deg, csum, N);
    k_scanmid<<<1, 512, 0, stream>>>(csum, cbase, rowstart, NCH, N);
    k_scan2<<<NCH, 256, 0, stream>>>(deg, cbase, rowstart, inv_deg, N);
    k_fill<<<2048, 256, 0, stream>>>(srcv, dstv, eattr, rowstart, deg, csr_rec, E, N);

    auto WT = [&](int m) { return wt + (size_t)m * 16384; };
    const int NB64 = (N + 63) / 64;
    const int GAGG = (N + 15) / 16;

    const unsigned short* xin = xb;
    for (int l = 0; l < 3; ++l) {
        unsigned short* gb = (l == 1) ? t3 : t2;   // xin rotates xb -> t2 -> t3 -> t2
        // g = relu(x @ W_lin + b_lin) @ Wmsg_top + b_msg   (h stays in LDS)
        k_gemm_s<false, true, 128, false><<<NB64, 256, 0, stream>>>(
            xin, WT(l), nullptr, nullptr, WT(3 + l), b_lin + l * HD, b_msg + l * HD, gb, N);
        // agg = inv_deg * sum relu(g[src] + attr*wlast)  -> t1
        k_agg<<<GAGG, 256, 0, stream>>>(
            gb, csr_rec, rowstart, inv_deg,
            W_msg + (size_t)l * (HD + 1) * HD + (size_t)HD * HD, t1, N);
        // x' = relu(agg @ W_l + x @ W_r + b_l) -> gb (g dead; gb != xin)
        k_gemm_s<true, false, 128, false><<<NB64, 256, 0, stream>>>(
            t1, WT(6 + l), xin, WT(9 + l), nullptr, b_l + l * HD, nullptr, gb, N);
        xin = gb;
    }
    // logits = relu(x @ W_dec + b_dec) @ W_fin + b_fin -> d_out (f32)
    k_gemm_s<false, true, 64, true><<<NB64, 256, 0, stream>>>(
        xin, WT(12), nullptr, nullptr, WT(13), b_dec, b_fin, (float*)d_out, N);
}